// Round 2
// baseline (5753.662 us; speedup 1.0000x reference)
//
#include <hip/hip_runtime.h>
#include <cstdint>
#include <cstddef>
#include <cmath>

#define DI __device__ __forceinline__

typedef float f32x4 __attribute__((ext_vector_type(4)));
typedef __bf16 bf16x8 __attribute__((ext_vector_type(8)));

static constexpr int TKN = 4096;   // B*S
static constexpr int SEQ = 2048;
static constexpr int DIM = 2048;
static constexpr int NH  = 16;

DI unsigned short f2bf(float f) {
  union { float f; unsigned u; } v; v.f = f;
  unsigned r = v.u + 0x7fffu + ((v.u >> 16) & 1u);
  return (unsigned short)(r >> 16);
}
DI float bf2f(unsigned short h) {
  union { unsigned u; float f; } v; v.u = ((unsigned)h) << 16;
  return v.f;
}
DI float bfb(unsigned bits16) {
  union { unsigned u; float f; } v; v.u = bits16 << 16;
  return v.f;
}
DI unsigned cvtpk(float lo, float hi) {
  unsigned r;
  asm("v_cvt_pk_bf16_f32 %0, %1, %2" : "=v"(r) : "v"(lo), "v"(hi));
  return r;
}
DI f32x4 mfma16(bf16x8 a, bf16x8 b, f32x4 c) {
  return __builtin_amdgcn_mfma_f32_16x16x32_bf16(a, b, c, 0, 0, 0);
}

// ================= precise split-bf16 (x3, 6-product) GEMM =================
// C[M,N] = A[M,K](f32) * B[N,K](f32)^T  with ~f32 accuracy via MFMA
enum { G3_F32 = 0, G3_RES = 1, G3_KV = 2 };

template<int EPI>
__global__ __launch_bounds__(256)
void gemm3(const float* __restrict__ A, const float* __restrict__ Bw,
           float* __restrict__ Cout, int M, int N, int K, int lda,
           const float* __restrict__ taux,
           unsigned short* __restrict__ k0p, unsigned short* __restrict__ k1p,
           unsigned short* __restrict__ v0p, unsigned short* __restrict__ v1p,
           unsigned short* __restrict__ v2p)
{
  constexpr int BM = 128, BN = 128, BK = 32, LDT = 40;
  __shared__ __align__(16) unsigned short As[3][BM * LDT];
  __shared__ __align__(16) unsigned short Bs[3][BN * LDT];
  int m0 = blockIdx.x * BM, n0 = blockIdx.y * BN;
  int tid = threadIdx.x, lane = tid & 63, wid = tid >> 6;
  int wm = (wid >> 1) * 64, wn = (wid & 1) * 64;
  int lr = lane & 15, lk = (lane >> 4) * 8;
  f32x4 acc[4][4] = {};

  for (int kt = 0; kt < K; kt += BK) {
    // stage A: 128x32 f32 -> 3 bf16 planes
    #pragma unroll
    for (int i = 0; i < 4; i++) {
      int vv = tid + i * 256, r = vv >> 3, c = (vv & 7) * 4;
      float4 d = {0.f, 0.f, 0.f, 0.f};
      if (m0 + r < M) d = *(const float4*)(A + (size_t)(m0 + r) * lda + kt + c);
      unsigned a01 = cvtpk(d.x, d.y), a23 = cvtpk(d.z, d.w);
      float rx = d.x - bfb(a01 & 0xffffu), ry = d.y - bfb(a01 >> 16);
      float rz = d.z - bfb(a23 & 0xffffu), rw = d.w - bfb(a23 >> 16);
      unsigned b01 = cvtpk(rx, ry), b23 = cvtpk(rz, rw);
      float sx = rx - bfb(b01 & 0xffffu), sy = ry - bfb(b01 >> 16);
      float sz = rz - bfb(b23 & 0xffffu), sw = rw - bfb(b23 >> 16);
      unsigned c01 = cvtpk(sx, sy), c23 = cvtpk(sz, sw);
      uint2 u0 = {a01, a23}, u1 = {b01, b23}, u2 = {c01, c23};
      *(uint2*)(&As[0][r * LDT + c]) = u0;
      *(uint2*)(&As[1][r * LDT + c]) = u1;
      *(uint2*)(&As[2][r * LDT + c]) = u2;
    }
    // stage B: 128x32 f32 -> 3 bf16 planes
    #pragma unroll
    for (int i = 0; i < 4; i++) {
      int vv = tid + i * 256, r = vv >> 3, c = (vv & 7) * 4;
      float4 d = {0.f, 0.f, 0.f, 0.f};
      if (n0 + r < N) d = *(const float4*)(Bw + (size_t)(n0 + r) * K + kt + c);
      unsigned a01 = cvtpk(d.x, d.y), a23 = cvtpk(d.z, d.w);
      float rx = d.x - bfb(a01 & 0xffffu), ry = d.y - bfb(a01 >> 16);
      float rz = d.z - bfb(a23 & 0xffffu), rw = d.w - bfb(a23 >> 16);
      unsigned b01 = cvtpk(rx, ry), b23 = cvtpk(rz, rw);
      float sx = rx - bfb(b01 & 0xffffu), sy = ry - bfb(b01 >> 16);
      float sz = rz - bfb(b23 & 0xffffu), sw = rw - bfb(b23 >> 16);
      unsigned c01 = cvtpk(sx, sy), c23 = cvtpk(sz, sw);
      uint2 u0 = {a01, a23}, u1 = {b01, b23}, u2 = {c01, c23};
      *(uint2*)(&Bs[0][r * LDT + c]) = u0;
      *(uint2*)(&Bs[1][r * LDT + c]) = u1;
      *(uint2*)(&Bs[2][r * LDT + c]) = u2;
    }
    __syncthreads();
    bf16x8 af[3][4], bfv[3][4];
    #pragma unroll
    for (int p = 0; p < 3; p++) {
      #pragma unroll
      for (int i = 0; i < 4; i++)
        af[p][i] = *(const bf16x8*)(&As[p][(wm + i * 16 + lr) * LDT + lk]);
      #pragma unroll
      for (int j = 0; j < 4; j++)
        bfv[p][j] = *(const bf16x8*)(&Bs[p][(wn + j * 16 + lr) * LDT + lk]);
    }
    #pragma unroll
    for (int i = 0; i < 4; i++)
      #pragma unroll
      for (int j = 0; j < 4; j++) {
        f32x4 t = acc[i][j];
        t = mfma16(af[0][i], bfv[0][j], t);
        t = mfma16(af[1][i], bfv[0][j], t);
        t = mfma16(af[0][i], bfv[1][j], t);
        t = mfma16(af[1][i], bfv[1][j], t);
        t = mfma16(af[2][i], bfv[0][j], t);
        t = mfma16(af[0][i], bfv[2][j], t);
        acc[i][j] = t;
      }
    __syncthreads();
  }

  int og = (lane >> 4) * 4;
  #pragma unroll
  for (int i = 0; i < 4; i++)
    #pragma unroll
    for (int p = 0; p < 4; p++) {
      int r = m0 + wm + i * 16 + og + p;
      if (r >= M) continue;
      #pragma unroll
      for (int j = 0; j < 4; j++) {
        int c = n0 + wn + j * 16 + lr;
        if (c >= N) continue;
        float v = acc[i][j][p];
        if (EPI == G3_F32) {
          Cout[(size_t)r * N + c] = v;
        } else if (EPI == G3_RES) {
          Cout[(size_t)r * N + c] = v + taux[(size_t)r * N + c];
        } else { // G3_KV: split k (x2 planes) / v (x3 planes)
          int hd = c >> 8, cc = c & 255;
          size_t base = ((size_t)r * NH + hd) * 128;
          unsigned short b0 = f2bf(v);
          float r1 = v - bf2f(b0);
          unsigned short b1 = f2bf(r1);
          if (cc < 128) {
            k0p[base + cc] = b0; k1p[base + cc] = b1;
          } else {
            float r2 = r1 - bf2f(b1);
            unsigned short b2 = f2bf(r2);
            v0p[base + cc - 128] = b0; v1p[base + cc - 128] = b1; v2p[base + cc - 128] = b2;
          }
        }
      }
    }
}

// ================= precise flash attention (split planes) =================
__global__ __launch_bounds__(256)
void attn3(const unsigned short* __restrict__ qs0, const unsigned short* __restrict__ qs1,
           const unsigned short* __restrict__ ks0, const unsigned short* __restrict__ ks1,
           const unsigned short* __restrict__ kp0, const unsigned short* __restrict__ kp1,
           const unsigned short* __restrict__ vs0, const unsigned short* __restrict__ vs1,
           const unsigned short* __restrict__ vs2,
           float* __restrict__ o, float scale)
{
  constexpr int KLD = 200; // 192+8 (u16), row = 400B (16B aligned)
  constexpr int VLD = 40;  // 32+8 (u16), row = 80B
  constexpr int PLD = 36;  // f32 cols, row = 144B
  __shared__ __align__(16) unsigned short Ks[2][32 * KLD];
  __shared__ __align__(16) unsigned short Vt[3][128 * VLD];
  __shared__ __align__(16) float Ps[4][16 * PLD];

  int qt = blockIdx.x, bh = blockIdx.y;
  int b = bh >> 4, h = bh & 15;
  int tid = threadIdx.x, lane = tid & 63, wid = tid >> 6;
  int lr = lane & 15, lg = lane >> 4, lk = lg * 8;
  int q0 = qt * 64;
  size_t tbase = (size_t)b * SEQ;

  bf16x8 qf[2][6];
  {
    size_t qoff = (tbase + q0 + wid * 16 + lr) * (size_t)3072 + h * 192;
    #pragma unroll
    for (int kc = 0; kc < 6; kc++) {
      qf[0][kc] = *(const bf16x8*)(qs0 + qoff + kc * 32 + lk);
      qf[1][kc] = *(const bf16x8*)(qs1 + qoff + kc * 32 + lk);
    }
  }

  f32x4 oacc[8] = {};
  float mrow[4], lrow[4];
  #pragma unroll
  for (int p = 0; p < 4; p++) { mrow[p] = -1e30f; lrow[p] = 0.f; }

  int nkt = 2 * qt + 2;
  for (int kt = 0; kt < nkt; kt++) {
    __syncthreads();
    int krow0 = kt * 32;
    // stage K planes (nope from ks*, pe from kp*)
    #pragma unroll
    for (int p = 0; p < 2; p++) {
      const unsigned short* knp = p ? ks1 : ks0;
      const unsigned short* kpp = p ? kp1 : kp0;
      #pragma unroll
      for (int i = 0; i < 2; i++) {
        int vv = tid + i * 256, r = vv >> 4, c8 = (vv & 15) * 8;
        int4 d = *(const int4*)(knp + ((tbase + krow0 + r) * (size_t)NH + h) * 128 + c8);
        *(int4*)(&Ks[p][r * KLD + c8]) = d;
      }
      {
        int r = tid >> 3, c8 = (tid & 7) * 8;
        int4 d = *(const int4*)(kpp + (tbase + krow0 + r) * (size_t)64 + c8);
        *(int4*)(&Ks[p][r * KLD + 128 + c8]) = d;
      }
    }
    // stage V planes transposed
    #pragma unroll
    for (int p = 0; p < 3; p++) {
      const unsigned short* vp = (p == 0) ? vs0 : (p == 1 ? vs1 : vs2);
      #pragma unroll
      for (int i = 0; i < 2; i++) {
        int vv = tid + i * 256, key = vv >> 4, d8 = (vv & 15) * 8;
        int4 d = *(const int4*)(vp + ((tbase + krow0 + key) * (size_t)NH + h) * 128 + d8);
        const unsigned short* ds_ = (const unsigned short*)&d;
        #pragma unroll
        for (int jj = 0; jj < 8; jj++) Vt[p][(d8 + jj) * VLD + key] = ds_[jj];
      }
    }
    __syncthreads();

    // QK^T, x2 split (4 products)
    f32x4 sacc[2] = {};
    #pragma unroll
    for (int j = 0; j < 2; j++)
      #pragma unroll
      for (int kc = 0; kc < 6; kc++) {
        bf16x8 kf0 = *(const bf16x8*)(&Ks[0][(j * 16 + lr) * KLD + kc * 32 + lk]);
        bf16x8 kf1 = *(const bf16x8*)(&Ks[1][(j * 16 + lr) * KLD + kc * 32 + lk]);
        f32x4 t = sacc[j];
        t = mfma16(qf[0][kc], kf0, t);
        t = mfma16(qf[1][kc], kf0, t);
        t = mfma16(qf[0][kc], kf1, t);
        t = mfma16(qf[1][kc], kf1, t);
        sacc[j] = t;
      }

    // online softmax
    bool tail = (kt >= 2 * qt);
    float fsc[4];
    #pragma unroll
    for (int p = 0; p < 4; p++) {
      float s0 = sacc[0][p] * scale, s1 = sacc[1][p] * scale;
      if (tail) {
        int qrow = q0 + wid * 16 + lg * 4 + p;
        if (krow0 + lr > qrow) s0 = -1e30f;
        if (krow0 + 16 + lr > qrow) s1 = -1e30f;
      }
      float mx = fmaxf(s0, s1);
      #pragma unroll
      for (int off = 1; off < 16; off <<= 1) mx = fmaxf(mx, __shfl_xor(mx, off));
      float mnew = fmaxf(mrow[p], mx);
      fsc[p] = __expf(mrow[p] - mnew);
      float e0 = __expf(s0 - mnew), e1 = __expf(s1 - mnew);
      float ssum = e0 + e1;
      #pragma unroll
      for (int off = 1; off < 16; off <<= 1) ssum += __shfl_xor(ssum, off);
      lrow[p] = lrow[p] * fsc[p] + ssum;
      mrow[p] = mnew;
      Ps[wid][(lg * 4 + p) * PLD + lr] = e0;
      Ps[wid][(lg * 4 + p) * PLD + 16 + lr] = e1;
    }
    #pragma unroll
    for (int jf = 0; jf < 8; jf++) {
      f32x4 t = oacc[jf];
      t[0] *= fsc[0]; t[1] *= fsc[1]; t[2] *= fsc[2]; t[3] *= fsc[3];
      oacc[jf] = t;
    }

    // P split x2 in-register
    f32x4 pva = *(const f32x4*)(&Ps[wid][lr * PLD + lk]);
    f32x4 pvb = *(const f32x4*)(&Ps[wid][lr * PLD + lk + 4]);
    unsigned u0 = cvtpk(pva[0], pva[1]), u1 = cvtpk(pva[2], pva[3]);
    unsigned u2 = cvtpk(pvb[0], pvb[1]), u3 = cvtpk(pvb[2], pvb[3]);
    float r0 = pva[0] - bfb(u0 & 0xffffu), r1 = pva[1] - bfb(u0 >> 16);
    float r2 = pva[2] - bfb(u1 & 0xffffu), r3 = pva[3] - bfb(u1 >> 16);
    float r4 = pvb[0] - bfb(u2 & 0xffffu), r5 = pvb[1] - bfb(u2 >> 16);
    float r6 = pvb[2] - bfb(u3 & 0xffffu), r7 = pvb[3] - bfb(u3 >> 16);
    unsigned w0 = cvtpk(r0, r1), w1 = cvtpk(r2, r3), w2 = cvtpk(r4, r5), w3 = cvtpk(r6, r7);
    union { unsigned u[4]; bf16x8 v; } pa0u, pa1u;
    pa0u.u[0] = u0; pa0u.u[1] = u1; pa0u.u[2] = u2; pa0u.u[3] = u3;
    pa1u.u[0] = w0; pa1u.u[1] = w1; pa1u.u[2] = w2; pa1u.u[3] = w3;

    // PV, P-x2 * V-x3 (5 products)
    #pragma unroll
    for (int jf = 0; jf < 8; jf++) {
      bf16x8 vf0 = *(const bf16x8*)(&Vt[0][(jf * 16 + lr) * VLD + lk]);
      bf16x8 vf1 = *(const bf16x8*)(&Vt[1][(jf * 16 + lr) * VLD + lk]);
      bf16x8 vf2 = *(const bf16x8*)(&Vt[2][(jf * 16 + lr) * VLD + lk]);
      f32x4 t = oacc[jf];
      t = mfma16(pa0u.v, vf0, t);
      t = mfma16(pa1u.v, vf0, t);
      t = mfma16(pa0u.v, vf1, t);
      t = mfma16(pa1u.v, vf1, t);
      t = mfma16(pa0u.v, vf2, t);
      oacc[jf] = t;
    }
  }

  #pragma unroll
  for (int p = 0; p < 4; p++) {
    float inv = 1.f / lrow[p];
    int qrow = q0 + wid * 16 + lg * 4 + p;
    float* op = o + (tbase + qrow) * (size_t)DIM + h * 128;
    #pragma unroll
    for (int jf = 0; jf < 8; jf++) op[jf * 16 + lr] = oacc[jf][p] * inv;
  }
}

// ================= bf16 GEMM for MoE/shared path =================
enum { EPI_BF16 = 0, EPI_F32 = 1, EPI_SILU = 2 };
enum { AM_DIRECT = 0, AM_LIST = 1, AM_OFF = 2 };

template<int EPI, int AMODE>
__global__ __launch_bounds__(256)
void gemm_bt(const unsigned short* __restrict__ A, const float* __restrict__ Bw,
             void* __restrict__ Cout, int M, int N, int K, int lda,
             const int* __restrict__ list, const int* __restrict__ basep,
             const int* __restrict__ counts, const unsigned short* __restrict__ tauxb)
{
  constexpr int BM = 128, BN = 128, BK = 64, LDT = 72;
  int rowbase = 0;
  if (AMODE != AM_DIRECT) {
    int z = blockIdx.z;
    M = counts[z];
    rowbase = basep[z];
    Bw += (size_t)z * N * K;
  }
  int m0 = blockIdx.x * BM;
  int n0 = blockIdx.y * BN;
  if (m0 >= M) return;

  __shared__ __align__(16) unsigned short As[BM * LDT];
  __shared__ __align__(16) unsigned short Bs[BN * LDT];

  int tid = threadIdx.x, lane = tid & 63, wid = tid >> 6;
  int wm = (wid >> 1) * 64, wn = (wid & 1) * 64;
  int lr = lane & 15, lk = (lane >> 4) * 8;
  f32x4 acc[4][4] = {};

  for (int kt = 0; kt < K; kt += BK) {
    #pragma unroll
    for (int i = 0; i < 4; i++) {
      int vv = tid + i * 256, r = vv >> 3, cv = (vv & 7) * 8;
      int4 d = {0, 0, 0, 0};
      int gr = m0 + r;
      if (gr < M) {
        const unsigned short* ap;
        if (AMODE == AM_LIST)      ap = A + (size_t)list[rowbase + gr] * lda;
        else if (AMODE == AM_OFF)  ap = A + (size_t)(rowbase + gr) * lda;
        else                       ap = A + (size_t)gr * lda;
        d = *(const int4*)(ap + kt + cv);
      }
      *(int4*)(&As[r * LDT + cv]) = d;
    }
    #pragma unroll
    for (int i = 0; i < 8; i++) {
      int vv = tid + i * 256, r = vv >> 4, cv = (vv & 15) * 4;
      float4 d = {0.f, 0.f, 0.f, 0.f};
      int gn = n0 + r;
      if (gn < N) d = *(const float4*)(Bw + (size_t)gn * K + kt + cv);
      ushort4 bb;
      bb.x = f2bf(d.x); bb.y = f2bf(d.y); bb.z = f2bf(d.z); bb.w = f2bf(d.w);
      *(ushort4*)(&Bs[r * LDT + cv]) = bb;
    }
    __syncthreads();
    #pragma unroll
    for (int ko = 0; ko < BK; ko += 32) {
      bf16x8 af[4], bfv[4];
      #pragma unroll
      for (int i = 0; i < 4; i++)
        af[i] = *(const bf16x8*)(&As[(wm + i * 16 + lr) * LDT + ko + lk]);
      #pragma unroll
      for (int j = 0; j < 4; j++)
        bfv[j] = *(const bf16x8*)(&Bs[(wn + j * 16 + lr) * LDT + ko + lk]);
      #pragma unroll
      for (int i = 0; i < 4; i++)
        #pragma unroll
        for (int j = 0; j < 4; j++)
          acc[i][j] = mfma16(af[i], bfv[j], acc[i][j]);
    }
    __syncthreads();
  }

  int og = (lane >> 4) * 4;
  #pragma unroll
  for (int i = 0; i < 4; i++)
    #pragma unroll
    for (int p = 0; p < 4; p++) {
      int r = m0 + wm + i * 16 + og + p;
      if (r >= M) continue;
      size_t outr = (AMODE == AM_DIRECT) ? (size_t)r : (size_t)(rowbase + r);
      #pragma unroll
      for (int j = 0; j < 4; j++) {
        int c = n0 + wn + j * 16 + lr;
        if (c >= N) continue;
        float v = acc[i][j][p];
        if (EPI == EPI_BF16) {
          ((unsigned short*)Cout)[outr * N + c] = f2bf(v);
        } else if (EPI == EPI_F32) {
          ((float*)Cout)[outr * N + c] = v;
        } else { // EPI_SILU: silu(taux)*v -> bf16
          float t = bf2f(tauxb[outr * N + c]);
          float s = t / (1.f + __expf(-t));
          ((unsigned short*)Cout)[outr * N + c] = f2bf(s * v);
        }
      }
    }
}

// ================= small kernels =================
template<int BF16OUT>
__global__ __launch_bounds__(256)
void rmsnorm_k(const float* __restrict__ x, const float* __restrict__ w, void* __restrict__ out)
{
  __shared__ float sred[4];
  int t = blockIdx.x, tid = threadIdx.x;
  const float* xp = x + (size_t)t * DIM;
  float vals[8];
  float ss = 0.f;
  #pragma unroll
  for (int i = 0; i < 8; i++) { float v = xp[tid + i * 256]; vals[i] = v; ss += v * v; }
  #pragma unroll
  for (int off = 32; off > 0; off >>= 1) ss += __shfl_xor(ss, off);
  if ((tid & 63) == 0) sred[tid >> 6] = ss;
  __syncthreads();
  ss = sred[0] + sred[1] + sred[2] + sred[3];
  float rstd = 1.f / sqrtf(ss / (float)DIM + 1e-6f);
  #pragma unroll
  for (int i = 0; i < 8; i++) {
    int d = tid + i * 256;
    float v = vals[i] * rstd * w[d];
    if (BF16OUT) ((unsigned short*)out)[(size_t)t * DIM + d] = f2bf(v);
    else         ((float*)out)[(size_t)t * DIM + d] = v;
  }
}

__global__ __launch_bounds__(256)
void kv_split(const float* __restrict__ kvraw, const float* __restrict__ kvw,
              float* __restrict__ c, unsigned short* __restrict__ kp0,
              unsigned short* __restrict__ kp1,
              const float* __restrict__ cosT, const float* __restrict__ sinT)
{
  __shared__ float sred[4];
  int t = blockIdx.x, tid = threadIdx.x;
  const float* xp = kvraw + (size_t)t * 576;
  float v0 = xp[tid], v1 = xp[tid + 256];
  float ss = v0 * v0 + v1 * v1;
  #pragma unroll
  for (int off = 32; off > 0; off >>= 1) ss += __shfl_xor(ss, off);
  if ((tid & 63) == 0) sred[tid >> 6] = ss;
  __syncthreads();
  ss = sred[0] + sred[1] + sred[2] + sred[3];
  float rstd = 1.f / sqrtf(ss / 512.f + 1e-6f);
  c[(size_t)t * 512 + tid] = v0 * rstd * kvw[tid];
  c[(size_t)t * 512 + tid + 256] = v1 * rstd * kvw[tid + 256];
  if (tid < 32) {
    int srow = t & (SEQ - 1);
    float a = xp[512 + tid * 2], bb = xp[512 + tid * 2 + 1];
    float cs = cosT[srow * 32 + tid], sn = sinT[srow * 32 + tid];
    float ra = a * cs - bb * sn, rb = a * sn + bb * cs;
    unsigned p0 = cvtpk(ra, rb);
    float qa = ra - bfb(p0 & 0xffffu), qb = rb - bfb(p0 >> 16);
    unsigned p1 = cvtpk(qa, qb);
    *(unsigned*)(&kp0[(size_t)t * 64 + tid * 2]) = p0;
    *(unsigned*)(&kp1[(size_t)t * 64 + tid * 2]) = p1;
  }
}

__global__ __launch_bounds__(256)
void rope_table(float* __restrict__ cosT, float* __restrict__ sinT, const int* __restrict__ sp)
{
  int i = blockIdx.x * 256 + threadIdx.x;
  if (i >= SEQ * 32) return;
  int j = i & 31, srow = i >> 5;
  float pos = (float)(srow + sp[0]);
  float inv = powf(10000.f, -(float)(2 * j) / 64.f);
  float ang = pos * inv;
  cosT[i] = cosf(ang);
  sinT[i] = sinf(ang);
}

__global__ __launch_bounds__(256)
void rope_q_split(const float* __restrict__ q, unsigned short* __restrict__ q0p,
                  unsigned short* __restrict__ q1p,
                  const float* __restrict__ cosT, const float* __restrict__ sinT)
{
  int t = blockIdx.x;
  int srow = t & (SEQ - 1);
  #pragma unroll
  for (int i = 0; i < 6; i++) {
    int pi = threadIdx.x + i * 256;     // pair index 0..1535
    int h = pi / 96, r = pi % 96;
    int base = h * 192;
    float a, bb;
    int e0;
    if (r < 64) {
      e0 = base + r * 2;
      a = q[(size_t)t * 3072 + e0]; bb = q[(size_t)t * 3072 + e0 + 1];
    } else {
      int j = r - 64;
      e0 = base + 128 + j * 2;
      float x0 = q[(size_t)t * 3072 + e0], x1 = q[(size_t)t * 3072 + e0 + 1];
      float cs = cosT[srow * 32 + j], sn = sinT[srow * 32 + j];
      a = x0 * cs - x1 * sn; bb = x0 * sn + x1 * cs;
    }
    unsigned p0 = cvtpk(a, bb);
    float ra = a - bfb(p0 & 0xffffu), rb = bb - bfb(p0 >> 16);
    unsigned p1 = cvtpk(ra, rb);
    *(unsigned*)(&q0p[(size_t)t * 3072 + e0]) = p0;
    *(unsigned*)(&q1p[(size_t)t * 3072 + e0]) = p1;
  }
}

__global__ __launch_bounds__(256)
void gate_topk(const float* __restrict__ first, const float* __restrict__ nw,
               const float* __restrict__ gwm, const float* __restrict__ gbias,
               int* __restrict__ idx, float* __restrict__ gw4, int* __restrict__ counts)
{
  __shared__ float sred[4];
  __shared__ float sacc[12][4];
  int t = blockIdx.x, tid = threadIdx.x;
  const float* xp = first + (size_t)t * DIM;
  float vals[8];
  float ss = 0.f;
  #pragma unroll
  for (int i = 0; i < 8; i++) { float v = xp[tid + i * 256]; vals[i] = v; ss += v * v; }
  #pragma unroll
  for (int off = 32; off > 0; off >>= 1) ss += __shfl_xor(ss, off);
  if ((tid & 63) == 0) sred[tid >> 6] = ss;
  __syncthreads();
  ss = sred[0] + sred[1] + sred[2] + sred[3];
  float rstd = 1.f / sqrtf(ss / (float)DIM + 1e-6f);
  float acc[12];
  #pragma unroll
  for (int e = 0; e < 12; e++) acc[e] = 0.f;
  #pragma unroll
  for (int i = 0; i < 8; i++) {
    int d = tid + i * 256;
    float v = vals[i] * rstd * nw[d];
    #pragma unroll
    for (int e = 0; e < 12; e++) acc[e] += v * gwm[e * DIM + d];
  }
  #pragma unroll
  for (int e = 0; e < 12; e++) {
    float a = acc[e];
    #pragma unroll
    for (int off = 32; off > 0; off >>= 1) a += __shfl_xor(a, off);
    if ((tid & 63) == 0) sacc[e][tid >> 6] = a;
  }
  __syncthreads();
  if (tid == 0) {
    float g[12], sc[12];
    #pragma unroll
    for (int e = 0; e < 12; e++) {
      float s = sacc[e][0] + sacc[e][1] + sacc[e][2] + sacc[e][3];
      g[e] = 1.f / (1.f + __expf(-s));
      sc[e] = g[e] + gbias[e];
    }
    bool taken[12] = {};
    int sel[4];
    float wsum = 0.f;
    #pragma unroll
    for (int s4 = 0; s4 < 4; s4++) {
      float best = -1e38f; int bi = 0;
      for (int e = 0; e < 12; e++)
        if (!taken[e] && sc[e] > best) { best = sc[e]; bi = e; }
      taken[bi] = true; sel[s4] = bi; wsum += g[bi];
    }
    #pragma unroll
    for (int s4 = 0; s4 < 4; s4++) {
      idx[t * 4 + s4] = sel[s4];
      gw4[t * 4 + s4] = g[sel[s4]] / wsum;
      atomicAdd(&counts[sel[s4]], 1);
    }
  }
}

__global__ void prefix12(const int* __restrict__ counts, int* __restrict__ basep,
                         int* __restrict__ cursor)
{
  if (threadIdx.x == 0) {
    int run = 0;
    for (int e = 0; e < 12; e++) { basep[e] = run; run += counts[e]; cursor[e] = 0; }
  }
}

__global__ __launch_bounds__(256)
void fill_lists(const int* __restrict__ idx, const int* __restrict__ basep,
                int* __restrict__ cursor, int* __restrict__ list, int* __restrict__ slotrow)
{
  int t = blockIdx.x * 256 + threadIdx.x;
  if (t >= TKN) return;
  #pragma unroll
  for (int s = 0; s < 4; s++) {
    int e = idx[t * 4 + s];
    int pos = atomicAdd(&cursor[e], 1);
    list[basep[e] + pos] = t;
    slotrow[t * 4 + s] = basep[e] + pos;
  }
}

__global__ __launch_bounds__(256)
void final_combine(const float* __restrict__ first, const unsigned short* __restrict__ yout,
                   const float* __restrict__ gw4, const int* __restrict__ slotrow,
                   float* __restrict__ out)
{
  int t = blockIdx.x, tid = threadIdx.x;
  int r0 = slotrow[t * 4], r1 = slotrow[t * 4 + 1], r2 = slotrow[t * 4 + 2], r3 = slotrow[t * 4 + 3];
  float w0 = gw4[t * 4], w1_ = gw4[t * 4 + 1], w2_ = gw4[t * 4 + 2], w3_ = gw4[t * 4 + 3];
  #pragma unroll
  for (int i = 0; i < 8; i++) {
    int d = tid + i * 256;
    size_t o = (size_t)t * DIM + d;
    out[o] = first[o] + out[o]
           + w0 * bf2f(yout[(size_t)r0 * DIM + d])
           + w1_ * bf2f(yout[(size_t)r1 * DIM + d])
           + w2_ * bf2f(yout[(size_t)r2 * DIM + d])
           + w3_ * bf2f(yout[(size_t)r3 * DIM + d]);
  }
}

// ================= launch =================
extern "C" void kernel_launch(void* const* d_in, const int* in_sizes, int n_in,
                              void* d_out, int out_size, void* d_ws, size_t ws_size,
                              hipStream_t stream)
{
  (void)in_sizes; (void)n_in; (void)out_size; (void)ws_size;
  const float* x      = (const float*)d_in[0];
  const int*   sp     = (const int*)d_in[1];
  const float* norm_w = (const float*)d_in[2];
  const float* wq     = (const float*)d_in[3];
  const float* wkv_a  = (const float*)d_in[4];
  const float* kvnw   = (const float*)d_in[5];
  const float* wkv_b  = (const float*)d_in[6];
  const float* wo     = (const float*)d_in[7];
  const float* gatew  = (const float*)d_in[8];
  const float* gateb  = (const float*)d_in[9];
  const float* w1     = (const float*)d_in[10];
  const float* w2     = (const float*)d_in[11];
  const float* w3     = (const float*)d_in[12];
  const float* sw1    = (const float*)d_in[13];
  const float* sw2    = (const float*)d_in[14];
  const float* sw3    = (const float*)d_in[15];
  float* out = (float*)d_out;
  char* ws = (char*)d_ws;

  // ---- arena (time-multiplexed; ~187 MB) ----
  const size_t off_hf   = 0;                    // 33,554,432 f32 h
  const size_t off_kvr  = 33554432ull;          //  9,437,184 f32 kv raw
  const size_t off_cf   = 42991616ull;          //  8,388,608 f32 c (latent)
  const size_t off_qs0  = 0;                    // 25,165,824 bf16 q plane0 (over hf/kvr: dead)
  const size_t off_qs1  = 25165824ull;          // 25,165,824 bf16 q plane1 (over kvr/cf: dead)
  const size_t off_qf   = 51380224ull;          // 50,331,648 f32 q
  const size_t off_of   = 51380224ull;          // 33,554,432 f32 o (over qf: dead)
  const size_t off_kp0  = 101711872ull;         //    524,288 kpe plane0
  const size_t off_kp1  = 102236160ull;         //    524,288 kpe plane1
  const size_t off_ks0  = 102760448ull;         // 16,777,216 k_nope plane0
  const size_t off_ks1  = 119537664ull;         // 16,777,216 k_nope plane1
  const size_t off_vs0  = 136314880ull;         // 16,777,216 v plane0
  const size_t off_vs1  = 153092096ull;         // 16,777,216 v plane1
  const size_t off_vs2  = 169869312ull;         // 16,777,216 v plane2 (ends 186,646,528)
  const size_t off_first= 0;                    // 33,554,432 f32 (over qs0: dead after attn)
  const size_t off_h2   = 33554432ull;          // 16,777,216 bf16 (over qs1: dead)
  const size_t off_t1   = 50331648ull;          // 16,777,216 bf16 (over of: dead after wo)
  const size_t off_as   = 67108864ull;          // 16,777,216 bf16
  const size_t off_yout = 50331648ull;          // 67,108,864 bf16 (t1/as dead at E3)
  const size_t off_ae   = 117440512ull;         // 33,554,432 bf16 (over ks1/vs0: dead)
  const size_t off_y1e  = 150994944ull;         // 33,554,432 bf16 (over vs1/vs2: dead)
  const size_t off_cos  = 186646528ull;
  const size_t off_sin  = off_cos + 262144ull;
  const size_t off_idx  = off_sin + 262144ull;
  const size_t off_gw4  = off_idx + 65536ull;
  const size_t off_list = off_gw4 + 65536ull;
  const size_t off_slot = off_list + 65536ull;
  const size_t off_cnt  = off_slot + 65536ull;
  const size_t off_cur  = off_cnt + 256ull;
  const size_t off_base = off_cur + 256ull;

  float* hf  = (float*)(ws + off_hf);
  float* kvr = (float*)(ws + off_kvr);
  float* cf  = (float*)(ws + off_cf);
  float* qf  = (float*)(ws + off_qf);
  float* of  = (float*)(ws + off_of);
  unsigned short* qs0 = (unsigned short*)(ws + off_qs0);
  unsigned short* qs1 = (unsigned short*)(ws + off_qs1);
  unsigned short* kp0 = (unsigned short*)(ws + off_kp0);
  unsigned short* kp1 = (unsigned short*)(ws + off_kp1);
  unsigned short* ks0 = (unsigned short*)(ws + off_ks0);
  unsigned short* ks1 = (unsigned short*)(ws + off_ks1);
  unsigned short* vs0 = (unsigned short*)(ws + off_vs0);
  unsigned short* vs1 = (unsigned short*)(ws + off_vs1);
  unsigned short* vs2 = (unsigned short*)(ws + off_vs2);
  float* firstb = (float*)(ws + off_first);
  unsigned short* h2b  = (unsigned short*)(ws + off_h2);
  unsigned short* t1b  = (unsigned short*)(ws + off_t1);
  unsigned short* asb  = (unsigned short*)(ws + off_as);
  unsigned short* y1eb = (unsigned short*)(ws + off_y1e);
  unsigned short* aeb  = (unsigned short*)(ws + off_ae);
  unsigned short* youtb= (unsigned short*)(ws + off_yout);
  float* cosT = (float*)(ws + off_cos);
  float* sinT = (float*)(ws + off_sin);
  int*   idxb = (int*)(ws + off_idx);
  float* gw4b = (float*)(ws + off_gw4);
  int*   listb= (int*)(ws + off_list);
  int*   slotb= (int*)(ws + off_slot);
  int*   cntb = (int*)(ws + off_cnt);
  int*   curb = (int*)(ws + off_cur);
  int*   baseb= (int*)(ws + off_base);

  hipMemsetAsync(ws + off_cnt, 0, 512, stream);

  rope_table<<<dim3((SEQ * 32 + 255) / 256), 256, 0, stream>>>(cosT, sinT, sp);
  rmsnorm_k<0><<<dim3(TKN), 256, 0, stream>>>(x, norm_w, hf);
  // precise projections (x3 split)
  gemm3<G3_F32><<<dim3(32, 24), 256, 0, stream>>>(hf, wq, qf, TKN, 3072, 2048, 2048,
      nullptr, nullptr, nullptr, nullptr, nullptr, nullptr);
  gemm3<G3_F32><<<dim3(32, 5), 256, 0, stream>>>(hf, wkv_a, kvr, TKN, 576, 2048, 2048,
      nullptr, nullptr, nullptr, nullptr, nullptr, nullptr);
  kv_split<<<dim3(TKN), 256, 0, stream>>>(kvr, kvnw, cf, kp0, kp1, cosT, sinT);
  gemm3<G3_KV><<<dim3(32, 32), 256, 0, stream>>>(cf, wkv_b, nullptr, TKN, 4096, 512, 512,
      nullptr, ks0, ks1, vs0, vs1, vs2);
  rope_q_split<<<dim3(TKN), 256, 0, stream>>>(qf, qs0, qs1, cosT, sinT);
  attn3<<<dim3(32, 32), 256, 0, stream>>>(qs0, qs1, ks0, ks1, kp0, kp1, vs0, vs1, vs2,
      of, 1.f / sqrtf(192.f));
  gemm3<G3_RES><<<dim3(32, 16), 256, 0, stream>>>(of, wo, firstb, TKN, 2048, 2048, 2048,
      x, nullptr, nullptr, nullptr, nullptr, nullptr);
  // gate (f32, from precise first)
  rmsnorm_k<1><<<dim3(TKN), 256, 0, stream>>>(firstb, norm_w, h2b);
  gate_topk<<<dim3(TKN), 256, 0, stream>>>(firstb, norm_w, gatew, gateb, idxb, gw4b, cntb);
  prefix12<<<dim3(1), 64, 0, stream>>>(cntb, baseb, curb);
  fill_lists<<<dim3(TKN / 256), 256, 0, stream>>>(idxb, baseb, curb, listb, slotb);
  // shared expert (bf16); ys accumulated directly into out
  gemm_bt<EPI_BF16, AM_DIRECT><<<dim3(32, 16), 256, 0, stream>>>(
      h2b, sw1, t1b, TKN, 2048, 2048, 2048, nullptr, nullptr, nullptr, nullptr);
  gemm_bt<EPI_SILU, AM_DIRECT><<<dim3(32, 16), 256, 0, stream>>>(
      h2b, sw3, asb, TKN, 2048, 2048, 2048, nullptr, nullptr, nullptr, t1b);
  gemm_bt<EPI_F32, AM_DIRECT><<<dim3(32, 16), 256, 0, stream>>>(
      asb, sw2, out, TKN, 2048, 2048, 2048, nullptr, nullptr, nullptr, nullptr);
  // routed experts (grouped, bf16)
  gemm_bt<EPI_BF16, AM_LIST><<<dim3(32, 8, 12), 256, 0, stream>>>(
      h2b, w1, y1eb, 0, 1024, 2048, 2048, listb, baseb, cntb, nullptr);
  gemm_bt<EPI_SILU, AM_LIST><<<dim3(32, 8, 12), 256, 0, stream>>>(
      h2b, w3, aeb, 0, 1024, 2048, 2048, listb, baseb, cntb, y1eb);
  gemm_bt<EPI_BF16, AM_OFF><<<dim3(32, 16, 12), 256, 0, stream>>>(
      aeb, w2, youtb, 0, 2048, 1024, 1024, listb, baseb, cntb, nullptr);
  final_combine<<<dim3(TKN), 256, 0, stream>>>(firstb, youtb, gw4b, slotb, out);
}

// Round 3
// 2941.102 us; speedup vs baseline: 1.9563x; 1.9563x over previous
//
#include <hip/hip_runtime.h>
#include <cstdint>
#include <cstddef>
#include <cmath>

#define DI __device__ __forceinline__
typedef float f32x4 __attribute__((ext_vector_type(4)));
typedef __bf16 bf16x8 __attribute__((ext_vector_type(8)));
typedef unsigned short u16;
typedef unsigned int u32;

static constexpr int TKN = 4096, SEQ = 2048, DIM = 2048, NH = 16;

DI u16 f2bf(float f) {
  union { float f; u32 u; } v; v.f = f;
  u32 r = v.u + 0x7fffu + ((v.u >> 16) & 1u);
  return (u16)(r >> 16);
}
DI float bf2f(u16 h) {
  union { u32 u; float f; } v; v.u = ((u32)h) << 16;
  return v.f;
}
DI f32x4 mfma16(bf16x8 a, bf16x8 b, f32x4 c) {
  return __builtin_amdgcn_mfma_f32_16x16x32_bf16(a, b, c, 0, 0, 0);
}
DI void gld16(const u16* g, u16* l) {
  __builtin_amdgcn_global_load_lds((const __attribute__((address_space(1))) u32*)g,
                                   (__attribute__((address_space(3))) u32*)l, 16, 0, 0);
}

// ================= unified m97-style GEMM =================
// C[M,N] = sum_seg A_plane[asg] [M,K] * B_plane[bsg] [N,K]^T   (bf16 MFMA)
enum { EF_F32 = 0, EF_BF16 = 1, EF_RES = 2, EF_KV = 3, EF_SILU = 4, EF_ATOM = 5, EF_QROPE = 6 };
enum { AM_DIR = 0, AM_LIST = 1, AM_OFF = 2 };

template<int EPI, int AMODE, int NSEG>
__global__ __launch_bounds__(256)
void gemm_f(const u16* __restrict__ A, const u16* __restrict__ B, void* __restrict__ C,
            int M, int N, int K, size_t apl, size_t bpl,
            const int* __restrict__ list, const int* __restrict__ basep,
            const int* __restrict__ counts,
            const void* __restrict__ aux, const float* __restrict__ gws,
            u16* __restrict__ kd0, u16* __restrict__ kd1, u16* __restrict__ vT,
            const float* __restrict__ cosT)
{
  constexpr int BM = 128, BK = 64;
  __shared__ __align__(16) u16 As[BM * BK];
  __shared__ __align__(16) u16 Bs[BM * BK];
  int rowbase = 0;
  if (AMODE != AM_DIR) {
    int z = blockIdx.z;
    M = counts[z];
    rowbase = basep[z];
    B += (size_t)z * (size_t)N * K;
  }
  int m0 = blockIdx.x * BM, n0 = blockIdx.y * BM;
  if (m0 >= M) return;
  int tid = threadIdx.x, lane = tid & 63, wid = tid >> 6;
  int wm = (wid >> 1) * 64, wn = (wid & 1) * 64;
  int lr = lane & 15, lk = (lane >> 4) * 8;

  // per-lane staging sources (16B per lane per chunk; LDS is linear lane*16)
  const u16* asrc[4];
  const u16* bsrc[4];
  int l8 = lane >> 3, c8 = (lane & 7) * 8;
  #pragma unroll
  for (int i = 0; i < 4; i++) {
    int chunk = wid * 4 + i;
    int ra = m0 + chunk * 8 + l8;
    size_t rowidx;
    if (AMODE == AM_LIST)      rowidx = (size_t)list[rowbase + (ra < M ? ra : 0)];
    else if (AMODE == AM_OFF)  rowidx = (size_t)(rowbase + (ra < M ? ra : 0));
    else                       rowidx = (size_t)ra;
    asrc[i] = A + rowidx * (size_t)K + c8;
    int rb = n0 + chunk * 8 + l8;
    if (rb >= N) rb = N - 1;
    bsrc[i] = B + (size_t)rb * K + c8;
  }

  f32x4 acc[4][4] = {};
  #pragma unroll 1
  for (int s = 0; s < NSEG; s++) {
    int sa = (s == 4) ? 2 : (s & 1);          // {0,1,0,1,2,0}
    int sb = (s == 5) ? 2 : ((s >> 1) & 1);   // {0,0,1,1,0,2}
    size_t ao = (size_t)sa * apl, bo = (size_t)sb * bpl;
    for (int kt = 0; kt < K; kt += BK) {
      #pragma unroll
      for (int i = 0; i < 4; i++) {
        gld16(asrc[i] + ao + kt, &As[(wid * 4 + i) * 512]);
        gld16(bsrc[i] + bo + kt, &Bs[(wid * 4 + i) * 512]);
      }
      __syncthreads();
      #pragma unroll
      for (int ko = 0; ko < BK; ko += 32) {
        bf16x8 af[4], bv[4];
        #pragma unroll
        for (int i = 0; i < 4; i++)
          af[i] = *(const bf16x8*)(&As[(wm + i * 16 + lr) * 64 + ko + lk]);
        #pragma unroll
        for (int j = 0; j < 4; j++)
          bv[j] = *(const bf16x8*)(&Bs[(wn + j * 16 + lr) * 64 + ko + lk]);
        #pragma unroll
        for (int i = 0; i < 4; i++)
          #pragma unroll
          for (int j = 0; j < 4; j++)
            acc[i][j] = mfma16(af[i], bv[j], acc[i][j]);
      }
      __syncthreads();
    }
  }

  int og = (lane >> 4) * 4;
  #pragma unroll
  for (int i = 0; i < 4; i++)
    #pragma unroll
    for (int p = 0; p < 4; p++) {
      int r = m0 + wm + i * 16 + og + p;
      if (EPI != EF_QROPE && EPI != EF_KV) { if (r >= M) continue; }
      size_t outr = (AMODE == AM_DIR) ? (size_t)r : (size_t)(rowbase + r);
      #pragma unroll
      for (int j = 0; j < 4; j++) {
        int c = n0 + wn + j * 16 + lr;
        float v = acc[i][j][p];
        if (EPI == EF_F32) {
          if (c < N) ((float*)C)[outr * N + c] = v;
        } else if (EPI == EF_BF16) {
          ((u16*)C)[outr * N + c] = f2bf(v);
        } else if (EPI == EF_RES) {
          ((float*)C)[outr * N + c] = v + ((const float*)aux)[outr * N + c];
        } else if (EPI == EF_SILU) {
          float t = bf2f(((const u16*)aux)[outr * N + c]);
          float sg = t / (1.f + __expf(-t));
          ((u16*)C)[outr * N + c] = f2bf(sg * v);
        } else if (EPI == EF_ATOM) {
          int tok = list[outr];
          float w = gws[outr];
          atomicAdd((float*)C + (size_t)tok * N + c, w * v);
        } else if (EPI == EF_QROPE) {
          // fused RoPE + 2-plane split; exact dims (no guards -> shfl-safe)
          int wi = c % 192;
          float vo = v;
          if (wi >= 128) {                 // uniform across wave (192%16==0)
            float part = __shfl_xor(v, 1);
            int jj = (wi - 128) >> 1;
            int srow = r & (SEQ - 1);
            float cs = cosT[srow * 32 + jj];
            float sn = ((const float*)aux)[srow * 32 + jj];
            vo = (c & 1) ? (part * sn + v * cs) : (v * cs - part * sn);
          }
          u16 b0 = f2bf(vo);
          u16 b1 = f2bf(vo - bf2f(b0));
          kd0[outr * (size_t)N + c] = b0;
          kd1[outr * (size_t)N + c] = b1;
        } else if (EPI == EF_KV) {
          int hd = c >> 8, cc = c & 255;
          u16 b0 = f2bf(v);
          float r1 = v - bf2f(b0);
          u16 b1 = f2bf(r1);
          if (cc < 128) {
            size_t base = ((size_t)r * NH + hd) * 128 + cc;
            kd0[base] = b0; kd1[base] = b1;
          } else {
            u16 b2 = f2bf(r1 - bf2f(b1));
            int bb = r >> 11, ss = r & (SEQ - 1);
            constexpr size_t VPL = (size_t)32 * 128 * 2048;
            size_t vb = ((size_t)((bb * 16 + hd) * 128 + (cc - 128))) * 2048 + ss;
            vT[vb] = b0; vT[VPL + vb] = b1; vT[2 * VPL + vb] = b2;
          }
        }
      }
    }
}

// ================= flash attention (paired q-tiles, transposed-V from global) ==
__global__ __launch_bounds__(256)
void attn3(const u16* __restrict__ q0p, const u16* __restrict__ q1p,
           const u16* __restrict__ k0p, const u16* __restrict__ k1p,
           const u16* __restrict__ kp0, const u16* __restrict__ kp1,
           const u16* __restrict__ vT, u16* __restrict__ o0, float scale)
{
  constexpr int KLD = 200, VLD = 40, PLD = 36;
  constexpr size_t VPL = (size_t)32 * 128 * 2048;
  constexpr size_t OPL = (size_t)TKN * DIM;
  __shared__ __align__(16) u16 Ks[2][32 * KLD];
  __shared__ __align__(16) u16 Vt[3][128 * VLD];
  __shared__ __align__(16) float Ps[4][16 * PLD];

  int bh = blockIdx.y;
  int b = bh >> 4, h = bh & 15;
  int tid = threadIdx.x, lane = tid & 63, wid = tid >> 6;
  int lr = lane & 15, lg = lane >> 4, lk = lg * 8;
  size_t tbase = (size_t)b * SEQ;
  const u16* vbase = vT + (size_t)bh * 128 * 2048;

  for (int half = 0; half < 2; half++) {
    int qt = half ? (31 - (int)blockIdx.x) : (int)blockIdx.x;
    int q0r = qt * 64;
    bf16x8 qf[2][6];
    {
      size_t qoff = (tbase + q0r + wid * 16 + lr) * (size_t)3072 + h * 192;
      #pragma unroll
      for (int kc = 0; kc < 6; kc++) {
        qf[0][kc] = *(const bf16x8*)(q0p + qoff + kc * 32 + lk);
        qf[1][kc] = *(const bf16x8*)(q1p + qoff + kc * 32 + lk);
      }
    }
    f32x4 oacc[8] = {};
    float mrow[4], lrow[4];
    #pragma unroll
    for (int p = 0; p < 4; p++) { mrow[p] = -1e30f; lrow[p] = 0.f; }

    int nkt = 2 * qt + 2;
    for (int kt = 0; kt < nkt; kt++) {
      __syncthreads();
      int kr0 = kt * 32;
      #pragma unroll
      for (int p = 0; p < 2; p++) {
        const u16* knp = p ? k1p : k0p;
        const u16* kpp = p ? kp1 : kp0;
        #pragma unroll
        for (int i = 0; i < 2; i++) {
          int vv = tid + i * 256, r = vv >> 4, cc8 = (vv & 15) * 8;
          int4 d = *(const int4*)(knp + ((tbase + kr0 + r) * (size_t)NH + h) * 128 + cc8);
          *(int4*)(&Ks[p][r * KLD + cc8]) = d;
        }
        {
          int r = tid >> 3, cc8 = (tid & 7) * 8;
          int4 d = *(const int4*)(kpp + (tbase + kr0 + r) * (size_t)64 + cc8);
          *(int4*)(&Ks[p][r * KLD + 128 + cc8]) = d;
        }
      }
      #pragma unroll
      for (int p = 0; p < 3; p++) {
        #pragma unroll
        for (int i = 0; i < 2; i++) {
          int vv = tid + i * 256, d = vv >> 2, cc8 = (vv & 3) * 8;
          int4 dd = *(const int4*)(vbase + p * VPL + (size_t)d * 2048 + kr0 + cc8);
          *(int4*)(&Vt[p][d * VLD + cc8]) = dd;
        }
      }
      __syncthreads();

      // QK^T (2x2 plane products)
      f32x4 sacc[2] = {};
      #pragma unroll
      for (int j = 0; j < 2; j++)
        #pragma unroll
        for (int kc = 0; kc < 6; kc++) {
          bf16x8 kf0 = *(const bf16x8*)(&Ks[0][(j * 16 + lr) * KLD + kc * 32 + lk]);
          bf16x8 kf1 = *(const bf16x8*)(&Ks[1][(j * 16 + lr) * KLD + kc * 32 + lk]);
          f32x4 t = sacc[j];
          t = mfma16(qf[0][kc], kf0, t);
          t = mfma16(qf[1][kc], kf0, t);
          t = mfma16(qf[0][kc], kf1, t);
          t = mfma16(qf[1][kc], kf1, t);
          sacc[j] = t;
        }

      bool tail = (kt >= 2 * qt);
      float fsc[4];
      #pragma unroll
      for (int p = 0; p < 4; p++) {
        float s0 = sacc[0][p] * scale, s1 = sacc[1][p] * scale;
        if (tail) {
          int qrow = q0r + wid * 16 + lg * 4 + p;
          if (kr0 + lr > qrow) s0 = -1e30f;
          if (kr0 + 16 + lr > qrow) s1 = -1e30f;
        }
        float mx = fmaxf(s0, s1);
        #pragma unroll
        for (int off = 1; off < 16; off <<= 1) mx = fmaxf(mx, __shfl_xor(mx, off));
        float mnew = fmaxf(mrow[p], mx);
        fsc[p] = __expf(mrow[p] - mnew);
        float e0 = __expf(s0 - mnew), e1 = __expf(s1 - mnew);
        float ssum = e0 + e1;
        #pragma unroll
        for (int off = 1; off < 16; off <<= 1) ssum += __shfl_xor(ssum, off);
        lrow[p] = lrow[p] * fsc[p] + ssum;
        mrow[p] = mnew;
        Ps[wid][(lg * 4 + p) * PLD + lr] = e0;
        Ps[wid][(lg * 4 + p) * PLD + 16 + lr] = e1;
      }
      #pragma unroll
      for (int jf = 0; jf < 8; jf++) {
        f32x4 t = oacc[jf];
        t[0] *= fsc[0]; t[1] *= fsc[1]; t[2] *= fsc[2]; t[3] *= fsc[3];
        oacc[jf] = t;
      }

      // P split x2 (in-register)
      f32x4 pva = *(const f32x4*)(&Ps[wid][lr * PLD + lk]);
      f32x4 pvb = *(const f32x4*)(&Ps[wid][lr * PLD + lk + 4]);
      union { u16 us[8]; bf16x8 v; } pa0u, pa1u;
      #pragma unroll
      for (int e = 0; e < 4; e++) {
        float va = pva[e];
        u16 b0 = f2bf(va); pa0u.us[e] = b0; pa1u.us[e] = f2bf(va - bf2f(b0));
        float vb = pvb[e];
        u16 c0 = f2bf(vb); pa0u.us[4 + e] = c0; pa1u.us[4 + e] = f2bf(vb - bf2f(c0));
      }

      // PV (P-x2 * V-x3, 5 products)
      #pragma unroll
      for (int jf = 0; jf < 8; jf++) {
        bf16x8 vf0 = *(const bf16x8*)(&Vt[0][(jf * 16 + lr) * VLD + lk]);
        bf16x8 vf1 = *(const bf16x8*)(&Vt[1][(jf * 16 + lr) * VLD + lk]);
        bf16x8 vf2 = *(const bf16x8*)(&Vt[2][(jf * 16 + lr) * VLD + lk]);
        f32x4 t = oacc[jf];
        t = mfma16(pa0u.v, vf0, t);
        t = mfma16(pa1u.v, vf0, t);
        t = mfma16(pa0u.v, vf1, t);
        t = mfma16(pa1u.v, vf1, t);
        t = mfma16(pa0u.v, vf2, t);
        oacc[jf] = t;
      }
    }

    // epilogue: 3-plane o write
    #pragma unroll
    for (int p = 0; p < 4; p++) {
      float inv = 1.f / lrow[p];
      int qrow = q0r + wid * 16 + lg * 4 + p;
      size_t base = (tbase + qrow) * (size_t)DIM + h * 128;
      #pragma unroll
      for (int jf = 0; jf < 8; jf++) {
        float val = oacc[jf][p] * inv;
        u16 b0 = f2bf(val);
        float r1 = val - bf2f(b0);
        u16 b1 = f2bf(r1);
        u16 b2 = f2bf(r1 - bf2f(b1));
        size_t idx = base + jf * 16 + lr;
        o0[idx] = b0; o0[OPL + idx] = b1; o0[2 * OPL + idx] = b2;
      }
    }
  }
}

// ================= small kernels =================
__global__ __launch_bounds__(256)
void rmsnorm3(const float* __restrict__ x, const float* __restrict__ w, u16* __restrict__ out)
{
  __shared__ float sred[4];
  constexpr size_t PL = (size_t)TKN * DIM;
  int t = blockIdx.x, tid = threadIdx.x;
  const float* xp = x + (size_t)t * DIM;
  float vals[8], ss = 0.f;
  #pragma unroll
  for (int i = 0; i < 8; i++) { float v = xp[tid + i * 256]; vals[i] = v; ss += v * v; }
  #pragma unroll
  for (int off = 32; off > 0; off >>= 1) ss += __shfl_xor(ss, off);
  if ((tid & 63) == 0) sred[tid >> 6] = ss;
  __syncthreads();
  ss = sred[0] + sred[1] + sred[2] + sred[3];
  float rstd = 1.f / sqrtf(ss / (float)DIM + 1e-6f);
  #pragma unroll
  for (int i = 0; i < 8; i++) {
    int d = tid + i * 256;
    float v = vals[i] * rstd * w[d];
    u16 b0 = f2bf(v);
    float r1 = v - bf2f(b0);
    u16 b1 = f2bf(r1);
    u16 b2 = f2bf(r1 - bf2f(b1));
    size_t o = (size_t)t * DIM + d;
    out[o] = b0; out[PL + o] = b1; out[2 * PL + o] = b2;
  }
}

__global__ __launch_bounds__(256)
void rmsnorm1(const float* __restrict__ x, const float* __restrict__ w, u16* __restrict__ out)
{
  __shared__ float sred[4];
  int t = blockIdx.x, tid = threadIdx.x;
  const float* xp = x + (size_t)t * DIM;
  float vals[8], ss = 0.f;
  #pragma unroll
  for (int i = 0; i < 8; i++) { float v = xp[tid + i * 256]; vals[i] = v; ss += v * v; }
  #pragma unroll
  for (int off = 32; off > 0; off >>= 1) ss += __shfl_xor(ss, off);
  if ((tid & 63) == 0) sred[tid >> 6] = ss;
  __syncthreads();
  ss = sred[0] + sred[1] + sred[2] + sred[3];
  float rstd = 1.f / sqrtf(ss / (float)DIM + 1e-6f);
  #pragma unroll
  for (int i = 0; i < 8; i++) {
    int d = tid + i * 256;
    out[(size_t)t * DIM + d] = f2bf(vals[i] * rstd * w[d]);
  }
}

__global__ __launch_bounds__(256)
void split3(const float* __restrict__ src, u16* __restrict__ dst, size_t n, size_t pl)
{
  size_t i0 = ((size_t)blockIdx.x * 256 + threadIdx.x) * 4;
  size_t stride = (size_t)gridDim.x * 1024;
  for (size_t i = i0; i < n; i += stride) {
    float4 d = *(const float4*)(src + i);
    ushort4 b0, b1, b2; float r;
    b0.x = f2bf(d.x); r = d.x - bf2f(b0.x); b1.x = f2bf(r); b2.x = f2bf(r - bf2f(b1.x));
    b0.y = f2bf(d.y); r = d.y - bf2f(b0.y); b1.y = f2bf(r); b2.y = f2bf(r - bf2f(b1.y));
    b0.z = f2bf(d.z); r = d.z - bf2f(b0.z); b1.z = f2bf(r); b2.z = f2bf(r - bf2f(b1.z));
    b0.w = f2bf(d.w); r = d.w - bf2f(b0.w); b1.w = f2bf(r); b2.w = f2bf(r - bf2f(b1.w));
    *(ushort4*)(dst + i) = b0;
    *(ushort4*)(dst + pl + i) = b1;
    *(ushort4*)(dst + 2 * pl + i) = b2;
  }
}

__global__ __launch_bounds__(256)
void cvt1(const float* __restrict__ src, u16* __restrict__ dst, size_t n)
{
  size_t i0 = ((size_t)blockIdx.x * 256 + threadIdx.x) * 4;
  size_t stride = (size_t)gridDim.x * 1024;
  for (size_t i = i0; i < n; i += stride) {
    float4 d = *(const float4*)(src + i);
    ushort4 b;
    b.x = f2bf(d.x); b.y = f2bf(d.y); b.z = f2bf(d.z); b.w = f2bf(d.w);
    *(ushort4*)(dst + i) = b;
  }
}

__global__ __launch_bounds__(256)
void kv_split(const float* __restrict__ kvraw, const float* __restrict__ kvw,
              u16* __restrict__ c0, u16* __restrict__ kp0, u16* __restrict__ kp1,
              const float* __restrict__ cosT, const float* __restrict__ sinT)
{
  __shared__ float sred[4];
  constexpr size_t CPL = (size_t)TKN * 512;
  int t = blockIdx.x, tid = threadIdx.x;
  const float* xp = kvraw + (size_t)t * 576;
  float v0 = xp[tid], v1 = xp[tid + 256];
  float ss = v0 * v0 + v1 * v1;
  #pragma unroll
  for (int off = 32; off > 0; off >>= 1) ss += __shfl_xor(ss, off);
  if ((tid & 63) == 0) sred[tid >> 6] = ss;
  __syncthreads();
  ss = sred[0] + sred[1] + sred[2] + sred[3];
  float rstd = 1.f / sqrtf(ss / 512.f + 1e-6f);
  #pragma unroll
  for (int half = 0; half < 2; half++) {
    float v = (half ? v1 : v0) * rstd * kvw[tid + half * 256];
    u16 b0 = f2bf(v);
    float r1 = v - bf2f(b0);
    u16 b1 = f2bf(r1);
    u16 b2 = f2bf(r1 - bf2f(b1));
    size_t o = (size_t)t * 512 + tid + half * 256;
    c0[o] = b0; c0[CPL + o] = b1; c0[2 * CPL + o] = b2;
  }
  if (tid < 32) {
    int srow = t & (SEQ - 1);
    float a = xp[512 + tid * 2], bb = xp[512 + tid * 2 + 1];
    float cs = cosT[srow * 32 + tid], sn = sinT[srow * 32 + tid];
    float ra = a * cs - bb * sn, rb = a * sn + bb * cs;
    u16 a0 = f2bf(ra), a1 = f2bf(ra - bf2f(a0));
    u16 c0b = f2bf(rb), c1 = f2bf(rb - bf2f(c0b));
    kp0[(size_t)t * 64 + tid * 2] = a0;     kp1[(size_t)t * 64 + tid * 2] = a1;
    kp0[(size_t)t * 64 + tid * 2 + 1] = c0b; kp1[(size_t)t * 64 + tid * 2 + 1] = c1;
  }
}

__global__ __launch_bounds__(256)
void rope_table(float* __restrict__ cosT, float* __restrict__ sinT, const int* __restrict__ sp)
{
  int i = blockIdx.x * 256 + threadIdx.x;
  if (i >= SEQ * 32) return;
  int j = i & 31, srow = i >> 5;
  float pos = (float)(srow + sp[0]);
  float inv = powf(10000.f, -(float)(2 * j) / 64.f);
  cosT[i] = cosf(pos * inv);
  sinT[i] = sinf(pos * inv);
}

__global__ __launch_bounds__(256)
void gate_topk(const float* __restrict__ first, const float* __restrict__ nw,
               const float* __restrict__ gwm, const float* __restrict__ gbias,
               int* __restrict__ idx, float* __restrict__ gw4, int* __restrict__ counts)
{
  __shared__ float sred[4];
  __shared__ float sacc[12][4];
  int t = blockIdx.x, tid = threadIdx.x;
  const float* xp = first + (size_t)t * DIM;
  float vals[8], ss = 0.f;
  #pragma unroll
  for (int i = 0; i < 8; i++) { float v = xp[tid + i * 256]; vals[i] = v; ss += v * v; }
  #pragma unroll
  for (int off = 32; off > 0; off >>= 1) ss += __shfl_xor(ss, off);
  if ((tid & 63) == 0) sred[tid >> 6] = ss;
  __syncthreads();
  ss = sred[0] + sred[1] + sred[2] + sred[3];
  float rstd = 1.f / sqrtf(ss / (float)DIM + 1e-6f);
  float acc[12];
  #pragma unroll
  for (int e = 0; e < 12; e++) acc[e] = 0.f;
  #pragma unroll
  for (int i = 0; i < 8; i++) {
    int d = tid + i * 256;
    float v = vals[i] * rstd * nw[d];
    #pragma unroll
    for (int e = 0; e < 12; e++) acc[e] += v * gwm[e * DIM + d];
  }
  #pragma unroll
  for (int e = 0; e < 12; e++) {
    float a = acc[e];
    #pragma unroll
    for (int off = 32; off > 0; off >>= 1) a += __shfl_xor(a, off);
    if ((tid & 63) == 0) sacc[e][tid >> 6] = a;
  }
  __syncthreads();
  if (tid == 0) {
    float g[12], sc[12];
    #pragma unroll
    for (int e = 0; e < 12; e++) {
      float s = sacc[e][0] + sacc[e][1] + sacc[e][2] + sacc[e][3];
      g[e] = 1.f / (1.f + __expf(-s));
      sc[e] = g[e] + gbias[e];
    }
    bool taken[12] = {};
    int sel[4];
    float wsum = 0.f;
    #pragma unroll
    for (int s4 = 0; s4 < 4; s4++) {
      float best = -1e38f; int bi = 0;
      for (int e = 0; e < 12; e++)
        if (!taken[e] && sc[e] > best) { best = sc[e]; bi = e; }
      taken[bi] = true; sel[s4] = bi; wsum += g[bi];
    }
    #pragma unroll
    for (int s4 = 0; s4 < 4; s4++) {
      idx[t * 4 + s4] = sel[s4];
      gw4[t * 4 + s4] = g[sel[s4]] / wsum;
      atomicAdd(&counts[sel[s4]], 1);
    }
  }
}

__global__ void prefix12(const int* __restrict__ counts, int* __restrict__ basep,
                         int* __restrict__ cursor)
{
  if (threadIdx.x == 0) {
    int run = 0;
    for (int e = 0; e < 12; e++) { basep[e] = run; run += counts[e]; cursor[e] = 0; }
  }
}

__global__ __launch_bounds__(256)
void fill_lists(const int* __restrict__ idx, const int* __restrict__ basep,
                int* __restrict__ cursor, int* __restrict__ list,
                const float* __restrict__ gw4, float* __restrict__ gws)
{
  int t = blockIdx.x * 256 + threadIdx.x;
  if (t >= TKN) return;
  #pragma unroll
  for (int s = 0; s < 4; s++) {
    int e = idx[t * 4 + s];
    int pos = atomicAdd(&cursor[e], 1);
    list[basep[e] + pos] = t;
    gws[basep[e] + pos] = gw4[t * 4 + s];
  }
}

__global__ __launch_bounds__(256)
void final_add(float* __restrict__ out, const float* __restrict__ first)
{
  size_t i0 = ((size_t)blockIdx.x * 256 + threadIdx.x) * 4;
  size_t stride = (size_t)gridDim.x * 1024;
  size_t n = (size_t)TKN * DIM;
  for (size_t i = i0; i < n; i += stride) {
    float4 a = *(const float4*)(out + i);
    float4 b = *(const float4*)(first + i);
    a.x += b.x; a.y += b.y; a.z += b.z; a.w += b.w;
    *(float4*)(out + i) = a;
  }
}

// ================= launch =================
extern "C" void kernel_launch(void* const* d_in, const int* in_sizes, int n_in,
                              void* d_out, int out_size, void* d_ws, size_t ws_size,
                              hipStream_t stream)
{
  (void)in_sizes; (void)n_in; (void)out_size; (void)ws_size;
  const float* x      = (const float*)d_in[0];
  const int*   sp     = (const int*)d_in[1];
  const float* norm_w = (const float*)d_in[2];
  const float* wq     = (const float*)d_in[3];
  const float* wkv_a  = (const float*)d_in[4];
  const float* kvnw   = (const float*)d_in[5];
  const float* wkv_b  = (const float*)d_in[6];
  const float* wo     = (const float*)d_in[7];
  const float* gatew  = (const float*)d_in[8];
  const float* gateb  = (const float*)d_in[9];
  const float* w1     = (const float*)d_in[10];
  const float* w2     = (const float*)d_in[11];
  const float* w3     = (const float*)d_in[12];
  const float* sw1    = (const float*)d_in[13];
  const float* sw2    = (const float*)d_in[14];
  const float* sw3    = (const float*)d_in[15];
  float* out = (float*)d_out;
  char* ws = (char*)d_ws;

  // ---- arena ----
  const size_t D0 = 0, D1 = 50331648ull, D2 = 100663296ull, D3 = 150994944ull;
  const size_t SM = 188743680ull;
  u16* hpl   = (u16*)(ws + D0);                       // 3 planes, pl 8388608
  u16* cpl   = (u16*)(ws + D0);                       // 3 planes, pl 2097152
  u16* wkvbp = (u16*)(ws + D0 + 12582912ull);         // 3 planes, pl 2097152
  u16* opl   = (u16*)(ws + D0);                       // 3 planes, pl 8388608
  u16* t1b   = (u16*)(ws + D0);
  u16* asb   = (u16*)(ws + D0 + 16777216ull);
  u16* aeb   = (u16*)(ws + D0);
  u16* qpl   = (u16*)(ws + D1);                       // 2 planes, pl 12582912
  u16* wexp  = (u16*)(ws + D1);
  u16* swp   = (u16*)(ws + D1 + 25165824ull);
  u16* vtp   = (u16*)(ws + D2);                       // 3 planes, pl 8388608
  float* firstb = (float*)(ws + D2);
  u16* h2b   = (u16*)(ws + D2 + 33554432ull);
  u16* wqp   = (u16*)(ws + D3);                       // 3 planes, pl 6291456
  u16* wkvap = (u16*)(ws + D3);                       // 3 planes, pl 1179648
  float* kvr = (float*)(ws + D3 + 7077888ull);
  u16* kpl0  = (u16*)(ws + D3);                       // 2 planes, pl 8388608
  u16* kpl1  = kpl0 + 8388608ull;
  u16* kpe0  = (u16*)(ws + D3 + 33554432ull);
  u16* kpe1  = kpe0 + 262144ull;
  u16* wop   = (u16*)(ws + D3);                       // 3 planes, pl 4194304
  u16* y1eb  = (u16*)(ws + D3);
  float* cosT = (float*)(ws + SM);
  float* sinT = (float*)(ws + SM + 262144ull);
  int*   idxb = (int*)(ws + SM + 524288ull);
  float* gw4b = (float*)(ws + SM + 589824ull);
  int*   listb= (int*)(ws + SM + 655360ull);
  float* gwsb = (float*)(ws + SM + 720896ull);
  int*   cntb = (int*)(ws + SM + 786432ull);
  int*   curb = (int*)(ws + SM + 786688ull);
  int*   baseb= (int*)(ws + SM + 786944ull);

  const size_t PL_TD = (size_t)TKN * DIM;  // 8388608

  hipMemsetAsync(cntb, 0, 256, stream);
  rope_table<<<dim3(256), 256, 0, stream>>>(cosT, sinT, sp);
  rmsnorm3<<<dim3(TKN), 256, 0, stream>>>(x, norm_w, hpl);

  // q = h @ wq^T  (fused RoPE + 2-plane split out)
  split3<<<dim3(1024), 256, 0, stream>>>(wq, wqp, (size_t)3072 * 2048, 6291456ull);
  gemm_f<EF_QROPE, AM_DIR, 6><<<dim3(32, 24), 256, 0, stream>>>(
      hpl, wqp, nullptr, TKN, 3072, 2048, PL_TD, 6291456ull,
      nullptr, nullptr, nullptr, sinT, nullptr, qpl, qpl + 12582912ull, nullptr, cosT);

  // kv = h @ wkv_a^T (f32)
  split3<<<dim3(512), 256, 0, stream>>>(wkv_a, wkvap, (size_t)576 * 2048, 1179648ull);
  gemm_f<EF_F32, AM_DIR, 6><<<dim3(32, 5), 256, 0, stream>>>(
      hpl, wkvap, kvr, TKN, 576, 2048, PL_TD, 1179648ull,
      nullptr, nullptr, nullptr, nullptr, nullptr, nullptr, nullptr, nullptr, nullptr);

  kv_split<<<dim3(TKN), 256, 0, stream>>>(kvr, kvnw, cpl, kpe0, kpe1, cosT, sinT);

  // k_nope/v = c @ wkv_b^T (split K planes + transposed V planes)
  split3<<<dim3(1024), 256, 0, stream>>>(wkv_b, wkvbp, (size_t)4096 * 512, 2097152ull);
  gemm_f<EF_KV, AM_DIR, 6><<<dim3(32, 32), 256, 0, stream>>>(
      cpl, wkvbp, nullptr, TKN, 4096, 512, 2097152ull, 2097152ull,
      nullptr, nullptr, nullptr, nullptr, nullptr, kpl0, kpl1, vtp, nullptr);

  attn3<<<dim3(16, 32), 256, 0, stream>>>(qpl, qpl + 12582912ull, kpl0, kpl1,
      kpe0, kpe1, vtp, opl, 1.f / sqrtf(192.f));

  // first = o @ wo^T + x
  split3<<<dim3(1024), 256, 0, stream>>>(wo, wop, (size_t)2048 * 2048, 4194304ull);
  gemm_f<EF_RES, AM_DIR, 6><<<dim3(32, 16), 256, 0, stream>>>(
      opl, wop, firstb, TKN, 2048, 2048, PL_TD, 4194304ull,
      nullptr, nullptr, nullptr, x, nullptr, nullptr, nullptr, nullptr, nullptr);

  rmsnorm1<<<dim3(TKN), 256, 0, stream>>>(firstb, norm_w, h2b);
  gate_topk<<<dim3(TKN), 256, 0, stream>>>(firstb, norm_w, gatew, gateb, idxb, gw4b, cntb);
  prefix12<<<dim3(1), 64, 0, stream>>>(cntb, baseb, curb);
  fill_lists<<<dim3(16), 256, 0, stream>>>(idxb, baseb, curb, listb, gw4b, gwsb);

  // shared expert -> out (write)
  cvt1<<<dim3(1024), 256, 0, stream>>>(sw1, swp, (size_t)2048 * 2048);
  cvt1<<<dim3(1024), 256, 0, stream>>>(sw3, swp + 4194304ull, (size_t)2048 * 2048);
  cvt1<<<dim3(1024), 256, 0, stream>>>(sw2, swp + 8388608ull, (size_t)2048 * 2048);
  gemm_f<EF_BF16, AM_DIR, 1><<<dim3(32, 16), 256, 0, stream>>>(
      h2b, swp, t1b, TKN, 2048, 2048, 0, 0,
      nullptr, nullptr, nullptr, nullptr, nullptr, nullptr, nullptr, nullptr, nullptr);
  gemm_f<EF_SILU, AM_DIR, 1><<<dim3(32, 16), 256, 0, stream>>>(
      h2b, swp + 4194304ull, asb, TKN, 2048, 2048, 0, 0,
      nullptr, nullptr, nullptr, t1b, nullptr, nullptr, nullptr, nullptr, nullptr);
  gemm_f<EF_F32, AM_DIR, 1><<<dim3(32, 16), 256, 0, stream>>>(
      asb, swp + 8388608ull, out, TKN, 2048, 2048, 0, 0,
      nullptr, nullptr, nullptr, nullptr, nullptr, nullptr, nullptr, nullptr, nullptr);

  // routed experts (two groups of 6), scatter-add into out
  for (int g = 0; g < 2; g++) {
    cvt1<<<dim3(2048), 256, 0, stream>>>(w1 + (size_t)g * 6 * 1024 * 2048, wexp,
                                         (size_t)6 * 1024 * 2048);
    gemm_f<EF_BF16, AM_LIST, 1><<<dim3(32, 8, 6), 256, 0, stream>>>(
        h2b, wexp, y1eb, 0, 1024, 2048, 0, 0,
        listb, baseb + g * 6, cntb + g * 6, nullptr, nullptr, nullptr, nullptr, nullptr, nullptr);
    cvt1<<<dim3(2048), 256, 0, stream>>>(w3 + (size_t)g * 6 * 1024 * 2048, wexp,
                                         (size_t)6 * 1024 * 2048);
    gemm_f<EF_SILU, AM_LIST, 1><<<dim3(32, 8, 6), 256, 0, stream>>>(
        h2b, wexp, aeb, 0, 1024, 2048, 0, 0,
        listb, baseb + g * 6, cntb + g * 6, y1eb, nullptr, nullptr, nullptr, nullptr, nullptr);
    cvt1<<<dim3(2048), 256, 0, stream>>>(w2 + (size_t)g * 6 * 2048 * 1024, wexp,
                                         (size_t)6 * 2048 * 1024);
    gemm_f<EF_ATOM, AM_OFF, 1><<<dim3(32, 16, 6), 256, 0, stream>>>(
        aeb, wexp, out, 0, 2048, 1024, 0, 0,
        listb, baseb + g * 6, cntb + g * 6, nullptr, gwsb, nullptr, nullptr, nullptr, nullptr);
  }

  final_add<<<dim3(2048), 256, 0, stream>>>(out, firstb);
}

// Round 4
// 2493.328 us; speedup vs baseline: 2.3076x; 1.1796x over previous
//
#include <hip/hip_runtime.h>
#include <cstdint>
#include <cstddef>
#include <cmath>

#define DI __device__ __forceinline__
typedef float f32x4 __attribute__((ext_vector_type(4)));
typedef __bf16 bf16x8 __attribute__((ext_vector_type(8)));
typedef unsigned short u16;
typedef unsigned int u32;

static constexpr int TKN = 4096, SEQ = 2048, DIM = 2048, NH = 16;

DI u16 f2bf(float f) {
  union { float f; u32 u; } v; v.f = f;
  u32 r = v.u + 0x7fffu + ((v.u >> 16) & 1u);
  return (u16)(r >> 16);
}
DI float bf2f(u16 h) {
  union { u32 u; float f; } v; v.u = ((u32)h) << 16;
  return v.f;
}
DI f32x4 mfma16(bf16x8 a, bf16x8 b, f32x4 c) {
  return __builtin_amdgcn_mfma_f32_16x16x32_bf16(a, b, c, 0, 0, 0);
}
DI void gld16(const u16* g, u16* l) {
  __builtin_amdgcn_global_load_lds((const __attribute__((address_space(1))) u32*)g,
                                   (__attribute__((address_space(3))) u32*)l, 16, 0, 0);
}

// ================= unified m97-style GEMM (T2-swizzled LDS) =================
// C[M,N] = sum_seg A_plane[asg] [M,K] * B_plane[bsg] [N,K]^T   (bf16 MFMA)
// LDS swizzle: global source slot pre-permuted (slot ^= row&7), LDS write linear
// (global_load_lds requirement), ds_read slot ^= row&7 (involution; rule #21).
enum { EF_F32 = 0, EF_BF16 = 1, EF_RES = 2, EF_KV = 3, EF_SILU = 4, EF_ATOM = 5, EF_QROPE = 6 };
enum { AM_DIR = 0, AM_LIST = 1, AM_OFF = 2 };

template<int EPI, int AMODE, int NSEG>
__global__ __launch_bounds__(256)
void gemm_f(const u16* __restrict__ A, const u16* __restrict__ B, void* __restrict__ C,
            int M, int N, int K, size_t apl, size_t bpl,
            const int* __restrict__ list, const int* __restrict__ basep,
            const int* __restrict__ counts,
            const void* __restrict__ aux, const float* __restrict__ gws,
            u16* __restrict__ kd0, u16* __restrict__ kd1, u16* __restrict__ vT,
            const float* __restrict__ cosT)
{
  constexpr int BM = 128, BK = 64;
  __shared__ __align__(16) u16 As[BM * BK];
  __shared__ __align__(16) u16 Bs[BM * BK];
  int rowbase = 0;
  if (AMODE != AM_DIR) {
    int z = blockIdx.z;
    M = counts[z];
    rowbase = basep[z];
    B += (size_t)z * (size_t)N * K;
  }
  int m0 = blockIdx.x * BM, n0 = blockIdx.y * BM;
  if (m0 >= M) return;
  int tid = threadIdx.x, lane = tid & 63, wid = tid >> 6;
  int wm = (wid >> 1) * 64, wn = (wid & 1) * 64;
  int lr = lane & 15, lk = (lane >> 4) * 8;

  // per-lane staging sources; slot pre-swizzled: slot ^= (row&7) == lane>>3
  const u16* asrc[4];
  const u16* bsrc[4];
  int l8 = lane >> 3, c8 = ((lane & 7) ^ l8) * 8;
  #pragma unroll
  for (int i = 0; i < 4; i++) {
    int chunk = wid * 4 + i;
    int ra = m0 + chunk * 8 + l8;
    size_t rowidx;
    if (AMODE == AM_LIST)      rowidx = (size_t)list[rowbase + (ra < M ? ra : 0)];
    else if (AMODE == AM_OFF)  rowidx = (size_t)(rowbase + (ra < M ? ra : 0));
    else                       rowidx = (size_t)ra;
    asrc[i] = A + rowidx * (size_t)K + c8;
    int rb = n0 + chunk * 8 + l8;
    if (rb >= N) rb = N - 1;
    bsrc[i] = B + (size_t)rb * K + c8;
  }

  f32x4 acc[4][4] = {};
  int sw = lr & 7;
  #pragma unroll 1
  for (int s = 0; s < NSEG; s++) {
    int sa = (s == 4) ? 2 : (s & 1);          // {0,1,0,1,2,0}
    int sb = (s == 5) ? 2 : ((s >> 1) & 1);   // {0,0,1,1,0,2}
    size_t ao = (size_t)sa * apl, bo = (size_t)sb * bpl;
    for (int kt = 0; kt < K; kt += BK) {
      #pragma unroll
      for (int i = 0; i < 4; i++) {
        gld16(asrc[i] + ao + kt, &As[(wid * 4 + i) * 512]);
        gld16(bsrc[i] + bo + kt, &Bs[(wid * 4 + i) * 512]);
      }
      __syncthreads();
      #pragma unroll
      for (int ko = 0; ko < BK; ko += 32) {
        bf16x8 af[4], bv[4];
        int sl = ((((ko + lk) >> 3) ^ sw) << 3);
        #pragma unroll
        for (int i = 0; i < 4; i++)
          af[i] = *(const bf16x8*)(&As[(wm + i * 16 + lr) * 64 + sl]);
        #pragma unroll
        for (int j = 0; j < 4; j++)
          bv[j] = *(const bf16x8*)(&Bs[(wn + j * 16 + lr) * 64 + sl]);
        #pragma unroll
        for (int i = 0; i < 4; i++)
          #pragma unroll
          for (int j = 0; j < 4; j++)
            acc[i][j] = mfma16(af[i], bv[j], acc[i][j]);
      }
      __syncthreads();
    }
  }

  int og = (lane >> 4) * 4;
  #pragma unroll
  for (int i = 0; i < 4; i++)
    #pragma unroll
    for (int p = 0; p < 4; p++) {
      int r = m0 + wm + i * 16 + og + p;
      if (EPI != EF_QROPE && EPI != EF_KV) { if (r >= M) continue; }
      size_t outr = (AMODE == AM_DIR) ? (size_t)r : (size_t)(rowbase + r);
      #pragma unroll
      for (int j = 0; j < 4; j++) {
        int c = n0 + wn + j * 16 + lr;
        float v = acc[i][j][p];
        if (EPI == EF_F32) {
          if (c < N) ((float*)C)[outr * N + c] = v;
        } else if (EPI == EF_BF16) {
          ((u16*)C)[outr * N + c] = f2bf(v);
        } else if (EPI == EF_RES) {
          ((float*)C)[outr * N + c] = v + ((const float*)aux)[outr * N + c];
        } else if (EPI == EF_SILU) {
          float t = bf2f(((const u16*)aux)[outr * N + c]);
          float sg = t / (1.f + __expf(-t));
          ((u16*)C)[outr * N + c] = f2bf(sg * v);
        } else if (EPI == EF_ATOM) {
          int tok = list[outr];
          float w = gws[outr];
          atomicAdd((float*)C + (size_t)tok * N + c, w * v);
        } else if (EPI == EF_QROPE) {
          // fused RoPE + 2-plane split; exact dims (no guards -> shfl-safe)
          int wi = c % 192;
          float vo = v;
          if (wi >= 128) {                 // uniform across wave (192%16==0)
            float part = __shfl_xor(v, 1);
            int jj = (wi - 128) >> 1;
            int srow = r & (SEQ - 1);
            float cs = cosT[srow * 32 + jj];
            float sn = ((const float*)aux)[srow * 32 + jj];
            vo = (c & 1) ? (part * sn + v * cs) : (v * cs - part * sn);
          }
          u16 b0 = f2bf(vo);
          u16 b1 = f2bf(vo - bf2f(b0));
          kd0[outr * (size_t)N + c] = b0;
          kd1[outr * (size_t)N + c] = b1;
        } else if (EPI == EF_KV) {
          int hd = c >> 8, cc = c & 255;
          u16 b0 = f2bf(v);
          float r1 = v - bf2f(b0);
          u16 b1 = f2bf(r1);
          if (cc < 128) {
            size_t base = ((size_t)r * NH + hd) * 128 + cc;
            kd0[base] = b0; kd1[base] = b1;
          } else {
            u16 b2 = f2bf(r1 - bf2f(b1));
            int bb = r >> 11, ss = r & (SEQ - 1);
            constexpr size_t VPL = (size_t)32 * 128 * 2048;
            size_t vb = ((size_t)((bb * 16 + hd) * 128 + (cc - 128))) * 2048 + ss;
            vT[vb] = b0; vT[VPL + vb] = b1; vT[2 * VPL + vb] = b2;
          }
        }
      }
    }
}

// ================= flash attention (paired q-tiles, transposed-V from global) ==
__global__ __launch_bounds__(256)
void attn3(const u16* __restrict__ q0p, const u16* __restrict__ q1p,
           const u16* __restrict__ k0p, const u16* __restrict__ k1p,
           const u16* __restrict__ kp0, const u16* __restrict__ kp1,
           const u16* __restrict__ vT, u16* __restrict__ o0, float scale)
{
  constexpr int KLD = 200, VLD = 40, PLD = 36;
  constexpr size_t VPL = (size_t)32 * 128 * 2048;
  constexpr size_t OPL = (size_t)TKN * DIM;
  __shared__ __align__(16) u16 Ks[2][32 * KLD];
  __shared__ __align__(16) u16 Vt[3][128 * VLD];
  __shared__ __align__(16) float Ps[4][16 * PLD];

  int bh = blockIdx.y;
  int b = bh >> 4, h = bh & 15;
  int tid = threadIdx.x, lane = tid & 63, wid = tid >> 6;
  int lr = lane & 15, lg = lane >> 4, lk = lg * 8;
  size_t tbase = (size_t)b * SEQ;
  const u16* vbase = vT + (size_t)bh * 128 * 2048;

  for (int half = 0; half < 2; half++) {
    int qt = half ? (31 - (int)blockIdx.x) : (int)blockIdx.x;
    int q0r = qt * 64;
    bf16x8 qf[2][6];
    {
      size_t qoff = (tbase + q0r + wid * 16 + lr) * (size_t)3072 + h * 192;
      #pragma unroll
      for (int kc = 0; kc < 6; kc++) {
        qf[0][kc] = *(const bf16x8*)(q0p + qoff + kc * 32 + lk);
        qf[1][kc] = *(const bf16x8*)(q1p + qoff + kc * 32 + lk);
      }
    }
    f32x4 oacc[8] = {};
    float mrow[4], lrow[4];
    #pragma unroll
    for (int p = 0; p < 4; p++) { mrow[p] = -1e30f; lrow[p] = 0.f; }

    int nkt = 2 * qt + 2;
    for (int kt = 0; kt < nkt; kt++) {
      __syncthreads();
      int kr0 = kt * 32;
      #pragma unroll
      for (int p = 0; p < 2; p++) {
        const u16* knp = p ? k1p : k0p;
        const u16* kpp = p ? kp1 : kp0;
        #pragma unroll
        for (int i = 0; i < 2; i++) {
          int vv = tid + i * 256, r = vv >> 4, cc8 = (vv & 15) * 8;
          int4 d = *(const int4*)(knp + ((tbase + kr0 + r) * (size_t)NH + h) * 128 + cc8);
          *(int4*)(&Ks[p][r * KLD + cc8]) = d;
        }
        {
          int r = tid >> 3, cc8 = (tid & 7) * 8;
          int4 d = *(const int4*)(kpp + (tbase + kr0 + r) * (size_t)64 + cc8);
          *(int4*)(&Ks[p][r * KLD + 128 + cc8]) = d;
        }
      }
      #pragma unroll
      for (int p = 0; p < 3; p++) {
        #pragma unroll
        for (int i = 0; i < 2; i++) {
          int vv = tid + i * 256, d = vv >> 2, cc8 = (vv & 3) * 8;
          int4 dd = *(const int4*)(vbase + p * VPL + (size_t)d * 2048 + kr0 + cc8);
          *(int4*)(&Vt[p][d * VLD + cc8]) = dd;
        }
      }
      __syncthreads();

      // QK^T (2x2 plane products)
      f32x4 sacc[2] = {};
      #pragma unroll
      for (int j = 0; j < 2; j++)
        #pragma unroll
        for (int kc = 0; kc < 6; kc++) {
          bf16x8 kf0 = *(const bf16x8*)(&Ks[0][(j * 16 + lr) * KLD + kc * 32 + lk]);
          bf16x8 kf1 = *(const bf16x8*)(&Ks[1][(j * 16 + lr) * KLD + kc * 32 + lk]);
          f32x4 t = sacc[j];
          t = mfma16(qf[0][kc], kf0, t);
          t = mfma16(qf[1][kc], kf0, t);
          t = mfma16(qf[0][kc], kf1, t);
          t = mfma16(qf[1][kc], kf1, t);
          sacc[j] = t;
        }

      bool tail = (kt >= 2 * qt);
      float fsc[4];
      #pragma unroll
      for (int p = 0; p < 4; p++) {
        float s0 = sacc[0][p] * scale, s1 = sacc[1][p] * scale;
        if (tail) {
          int qrow = q0r + wid * 16 + lg * 4 + p;
          if (kr0 + lr > qrow) s0 = -1e30f;
          if (kr0 + 16 + lr > qrow) s1 = -1e30f;
        }
        float mx = fmaxf(s0, s1);
        #pragma unroll
        for (int off = 1; off < 16; off <<= 1) mx = fmaxf(mx, __shfl_xor(mx, off));
        float mnew = fmaxf(mrow[p], mx);
        fsc[p] = __expf(mrow[p] - mnew);
        float e0 = __expf(s0 - mnew), e1 = __expf(s1 - mnew);
        float ssum = e0 + e1;
        #pragma unroll
        for (int off = 1; off < 16; off <<= 1) ssum += __shfl_xor(ssum, off);
        lrow[p] = lrow[p] * fsc[p] + ssum;
        mrow[p] = mnew;
        Ps[wid][(lg * 4 + p) * PLD + lr] = e0;
        Ps[wid][(lg * 4 + p) * PLD + 16 + lr] = e1;
      }
      #pragma unroll
      for (int jf = 0; jf < 8; jf++) {
        f32x4 t = oacc[jf];
        t[0] *= fsc[0]; t[1] *= fsc[1]; t[2] *= fsc[2]; t[3] *= fsc[3];
        oacc[jf] = t;
      }

      // P split x2 (in-register)
      f32x4 pva = *(const f32x4*)(&Ps[wid][lr * PLD + lk]);
      f32x4 pvb = *(const f32x4*)(&Ps[wid][lr * PLD + lk + 4]);
      union { u16 us[8]; bf16x8 v; } pa0u, pa1u;
      #pragma unroll
      for (int e = 0; e < 4; e++) {
        float va = pva[e];
        u16 b0 = f2bf(va); pa0u.us[e] = b0; pa1u.us[e] = f2bf(va - bf2f(b0));
        float vb = pvb[e];
        u16 c0 = f2bf(vb); pa0u.us[4 + e] = c0; pa1u.us[4 + e] = f2bf(vb - bf2f(c0));
      }

      // PV (P-x2 * V-x3, 5 products)
      #pragma unroll
      for (int jf = 0; jf < 8; jf++) {
        bf16x8 vf0 = *(const bf16x8*)(&Vt[0][(jf * 16 + lr) * VLD + lk]);
        bf16x8 vf1 = *(const bf16x8*)(&Vt[1][(jf * 16 + lr) * VLD + lk]);
        bf16x8 vf2 = *(const bf16x8*)(&Vt[2][(jf * 16 + lr) * VLD + lk]);
        f32x4 t = oacc[jf];
        t = mfma16(pa0u.v, vf0, t);
        t = mfma16(pa1u.v, vf0, t);
        t = mfma16(pa0u.v, vf1, t);
        t = mfma16(pa1u.v, vf1, t);
        t = mfma16(pa0u.v, vf2, t);
        oacc[jf] = t;
      }
    }

    // epilogue: 3-plane o write
    #pragma unroll
    for (int p = 0; p < 4; p++) {
      float inv = 1.f / lrow[p];
      int qrow = q0r + wid * 16 + lg * 4 + p;
      size_t base = (tbase + qrow) * (size_t)DIM + h * 128;
      #pragma unroll
      for (int jf = 0; jf < 8; jf++) {
        float val = oacc[jf][p] * inv;
        u16 b0 = f2bf(val);
        float r1 = val - bf2f(b0);
        u16 b1 = f2bf(r1);
        u16 b2 = f2bf(r1 - bf2f(b1));
        size_t idx = base + jf * 16 + lr;
        o0[idx] = b0; o0[OPL + idx] = b1; o0[2 * OPL + idx] = b2;
      }
    }
  }
}

// ================= small kernels =================
__global__ __launch_bounds__(256)
void rmsnorm3(const float* __restrict__ x, const float* __restrict__ w, u16* __restrict__ out)
{
  __shared__ float sred[4];
  constexpr size_t PL = (size_t)TKN * DIM;
  int t = blockIdx.x, tid = threadIdx.x;
  const float* xp = x + (size_t)t * DIM;
  float vals[8], ss = 0.f;
  #pragma unroll
  for (int i = 0; i < 8; i++) { float v = xp[tid + i * 256]; vals[i] = v; ss += v * v; }
  #pragma unroll
  for (int off = 32; off > 0; off >>= 1) ss += __shfl_xor(ss, off);
  if ((tid & 63) == 0) sred[tid >> 6] = ss;
  __syncthreads();
  ss = sred[0] + sred[1] + sred[2] + sred[3];
  float rstd = 1.f / sqrtf(ss / (float)DIM + 1e-6f);
  #pragma unroll
  for (int i = 0; i < 8; i++) {
    int d = tid + i * 256;
    float v = vals[i] * rstd * w[d];
    u16 b0 = f2bf(v);
    float r1 = v - bf2f(b0);
    u16 b1 = f2bf(r1);
    u16 b2 = f2bf(r1 - bf2f(b1));
    size_t o = (size_t)t * DIM + d;
    out[o] = b0; out[PL + o] = b1; out[2 * PL + o] = b2;
  }
}

__global__ __launch_bounds__(256)
void rmsnorm1(const float* __restrict__ x, const float* __restrict__ w, u16* __restrict__ out)
{
  __shared__ float sred[4];
  int t = blockIdx.x, tid = threadIdx.x;
  const float* xp = x + (size_t)t * DIM;
  float vals[8], ss = 0.f;
  #pragma unroll
  for (int i = 0; i < 8; i++) { float v = xp[tid + i * 256]; vals[i] = v; ss += v * v; }
  #pragma unroll
  for (int off = 32; off > 0; off >>= 1) ss += __shfl_xor(ss, off);
  if ((tid & 63) == 0) sred[tid >> 6] = ss;
  __syncthreads();
  ss = sred[0] + sred[1] + sred[2] + sred[3];
  float rstd = 1.f / sqrtf(ss / (float)DIM + 1e-6f);
  #pragma unroll
  for (int i = 0; i < 8; i++) {
    int d = tid + i * 256;
    out[(size_t)t * DIM + d] = f2bf(vals[i] * rstd * w[d]);
  }
}

__global__ __launch_bounds__(256)
void split3(const float* __restrict__ src, u16* __restrict__ dst, size_t n, size_t pl)
{
  size_t i0 = ((size_t)blockIdx.x * 256 + threadIdx.x) * 4;
  size_t stride = (size_t)gridDim.x * 1024;
  for (size_t i = i0; i < n; i += stride) {
    float4 d = *(const float4*)(src + i);
    ushort4 b0, b1, b2; float r;
    b0.x = f2bf(d.x); r = d.x - bf2f(b0.x); b1.x = f2bf(r); b2.x = f2bf(r - bf2f(b1.x));
    b0.y = f2bf(d.y); r = d.y - bf2f(b0.y); b1.y = f2bf(r); b2.y = f2bf(r - bf2f(b1.y));
    b0.z = f2bf(d.z); r = d.z - bf2f(b0.z); b1.z = f2bf(r); b2.z = f2bf(r - bf2f(b1.z));
    b0.w = f2bf(d.w); r = d.w - bf2f(b0.w); b1.w = f2bf(r); b2.w = f2bf(r - bf2f(b1.w));
    *(ushort4*)(dst + i) = b0;
    *(ushort4*)(dst + pl + i) = b1;
    *(ushort4*)(dst + 2 * pl + i) = b2;
  }
}

__global__ __launch_bounds__(256)
void cvt1(const float* __restrict__ src, u16* __restrict__ dst, size_t n)
{
  size_t i0 = ((size_t)blockIdx.x * 256 + threadIdx.x) * 4;
  size_t stride = (size_t)gridDim.x * 1024;
  for (size_t i = i0; i < n; i += stride) {
    float4 d = *(const float4*)(src + i);
    ushort4 b;
    b.x = f2bf(d.x); b.y = f2bf(d.y); b.z = f2bf(d.z); b.w = f2bf(d.w);
    *(ushort4*)(dst + i) = b;
  }
}

__global__ __launch_bounds__(256)
void kv_split(const float* __restrict__ kvraw, const float* __restrict__ kvw,
              u16* __restrict__ c0, u16* __restrict__ kp0, u16* __restrict__ kp1,
              const float* __restrict__ cosT, const float* __restrict__ sinT)
{
  __shared__ float sred[4];
  constexpr size_t CPL = (size_t)TKN * 512;
  int t = blockIdx.x, tid = threadIdx.x;
  const float* xp = kvraw + (size_t)t * 576;
  float v0 = xp[tid], v1 = xp[tid + 256];
  float ss = v0 * v0 + v1 * v1;
  #pragma unroll
  for (int off = 32; off > 0; off >>= 1) ss += __shfl_xor(ss, off);
  if ((tid & 63) == 0) sred[tid >> 6] = ss;
  __syncthreads();
  ss = sred[0] + sred[1] + sred[2] + sred[3];
  float rstd = 1.f / sqrtf(ss / 512.f + 1e-6f);
  #pragma unroll
  for (int half = 0; half < 2; half++) {
    float v = (half ? v1 : v0) * rstd * kvw[tid + half * 256];
    u16 b0 = f2bf(v);
    float r1 = v - bf2f(b0);
    u16 b1 = f2bf(r1);
    u16 b2 = f2bf(r1 - bf2f(b1));
    size_t o = (size_t)t * 512 + tid + half * 256;
    c0[o] = b0; c0[CPL + o] = b1; c0[2 * CPL + o] = b2;
  }
  if (tid < 32) {
    int srow = t & (SEQ - 1);
    float a = xp[512 + tid * 2], bb = xp[512 + tid * 2 + 1];
    float cs = cosT[srow * 32 + tid], sn = sinT[srow * 32 + tid];
    float ra = a * cs - bb * sn, rb = a * sn + bb * cs;
    u16 a0 = f2bf(ra), a1 = f2bf(ra - bf2f(a0));
    u16 c0b = f2bf(rb), c1 = f2bf(rb - bf2f(c0b));
    kp0[(size_t)t * 64 + tid * 2] = a0;     kp1[(size_t)t * 64 + tid * 2] = a1;
    kp0[(size_t)t * 64 + tid * 2 + 1] = c0b; kp1[(size_t)t * 64 + tid * 2 + 1] = c1;
  }
}

__global__ __launch_bounds__(256)
void rope_table(float* __restrict__ cosT, float* __restrict__ sinT, const int* __restrict__ sp)
{
  int i = blockIdx.x * 256 + threadIdx.x;
  if (i >= SEQ * 32) return;
  int j = i & 31, srow = i >> 5;
  float pos = (float)(srow + sp[0]);
  float inv = powf(10000.f, -(float)(2 * j) / 64.f);
  cosT[i] = cosf(pos * inv);
  sinT[i] = sinf(pos * inv);
}

__global__ __launch_bounds__(256)
void gate_topk(const float* __restrict__ first, const float* __restrict__ nw,
               const float* __restrict__ gwm, const float* __restrict__ gbias,
               int* __restrict__ idx, float* __restrict__ gw4, int* __restrict__ counts)
{
  __shared__ float sred[4];
  __shared__ float sacc[12][4];
  int t = blockIdx.x, tid = threadIdx.x;
  const float* xp = first + (size_t)t * DIM;
  float vals[8], ss = 0.f;
  #pragma unroll
  for (int i = 0; i < 8; i++) { float v = xp[tid + i * 256]; vals[i] = v; ss += v * v; }
  #pragma unroll
  for (int off = 32; off > 0; off >>= 1) ss += __shfl_xor(ss, off);
  if ((tid & 63) == 0) sred[tid >> 6] = ss;
  __syncthreads();
  ss = sred[0] + sred[1] + sred[2] + sred[3];
  float rstd = 1.f / sqrtf(ss / (float)DIM + 1e-6f);
  float acc[12];
  #pragma unroll
  for (int e = 0; e < 12; e++) acc[e] = 0.f;
  #pragma unroll
  for (int i = 0; i < 8; i++) {
    int d = tid + i * 256;
    float v = vals[i] * rstd * nw[d];
    #pragma unroll
    for (int e = 0; e < 12; e++) acc[e] += v * gwm[e * DIM + d];
  }
  #pragma unroll
  for (int e = 0; e < 12; e++) {
    float a = acc[e];
    #pragma unroll
    for (int off = 32; off > 0; off >>= 1) a += __shfl_xor(a, off);
    if ((tid & 63) == 0) sacc[e][tid >> 6] = a;
  }
  __syncthreads();
  if (tid == 0) {
    float g[12], sc[12];
    #pragma unroll
    for (int e = 0; e < 12; e++) {
      float s = sacc[e][0] + sacc[e][1] + sacc[e][2] + sacc[e][3];
      g[e] = 1.f / (1.f + __expf(-s));
      sc[e] = g[e] + gbias[e];
    }
    bool taken[12] = {};
    int sel[4];
    float wsum = 0.f;
    #pragma unroll
    for (int s4 = 0; s4 < 4; s4++) {
      float best = -1e38f; int bi = 0;
      for (int e = 0; e < 12; e++)
        if (!taken[e] && sc[e] > best) { best = sc[e]; bi = e; }
      taken[bi] = true; sel[s4] = bi; wsum += g[bi];
    }
    #pragma unroll
    for (int s4 = 0; s4 < 4; s4++) {
      idx[t * 4 + s4] = sel[s4];
      gw4[t * 4 + s4] = g[sel[s4]] / wsum;
      atomicAdd(&counts[sel[s4]], 1);
    }
  }
}

__global__ void prefix12(const int* __restrict__ counts, int* __restrict__ basep,
                         int* __restrict__ cursor)
{
  if (threadIdx.x == 0) {
    int run = 0;
    for (int e = 0; e < 12; e++) { basep[e] = run; run += counts[e]; cursor[e] = 0; }
  }
}

__global__ __launch_bounds__(256)
void fill_lists(const int* __restrict__ idx, const int* __restrict__ basep,
                int* __restrict__ cursor, int* __restrict__ list,
                const float* __restrict__ gw4, float* __restrict__ gws)
{
  int t = blockIdx.x * 256 + threadIdx.x;
  if (t >= TKN) return;
  #pragma unroll
  for (int s = 0; s < 4; s++) {
    int e = idx[t * 4 + s];
    int pos = atomicAdd(&cursor[e], 1);
    list[basep[e] + pos] = t;
    gws[basep[e] + pos] = gw4[t * 4 + s];
  }
}

__global__ __launch_bounds__(256)
void final_add(float* __restrict__ out, const float* __restrict__ first)
{
  size_t i0 = ((size_t)blockIdx.x * 256 + threadIdx.x) * 4;
  size_t stride = (size_t)gridDim.x * 1024;
  size_t n = (size_t)TKN * DIM;
  for (size_t i = i0; i < n; i += stride) {
    float4 a = *(const float4*)(out + i);
    float4 b = *(const float4*)(first + i);
    a.x += b.x; a.y += b.y; a.z += b.z; a.w += b.w;
    *(float4*)(out + i) = a;
  }
}

// ================= launch =================
extern "C" void kernel_launch(void* const* d_in, const int* in_sizes, int n_in,
                              void* d_out, int out_size, void* d_ws, size_t ws_size,
                              hipStream_t stream)
{
  (void)in_sizes; (void)n_in; (void)out_size; (void)ws_size;
  const float* x      = (const float*)d_in[0];
  const int*   sp     = (const int*)d_in[1];
  const float* norm_w = (const float*)d_in[2];
  const float* wq     = (const float*)d_in[3];
  const float* wkv_a  = (const float*)d_in[4];
  const float* kvnw   = (const float*)d_in[5];
  const float* wkv_b  = (const float*)d_in[6];
  const float* wo     = (const float*)d_in[7];
  const float* gatew  = (const float*)d_in[8];
  const float* gateb  = (const float*)d_in[9];
  const float* w1     = (const float*)d_in[10];
  const float* w2     = (const float*)d_in[11];
  const float* w3     = (const float*)d_in[12];
  const float* sw1    = (const float*)d_in[13];
  const float* sw2    = (const float*)d_in[14];
  const float* sw3    = (const float*)d_in[15];
  float* out = (float*)d_out;
  char* ws = (char*)d_ws;

  // ---- arena ----
  const size_t D0 = 0, D1 = 50331648ull, D2 = 100663296ull, D3 = 150994944ull;
  const size_t SM = 188743680ull;
  u16* hpl   = (u16*)(ws + D0);                       // 3 planes, pl 8388608
  u16* cpl   = (u16*)(ws + D0);                       // 3 planes, pl 2097152
  u16* wkvbp = (u16*)(ws + D0 + 12582912ull);         // 3 planes, pl 2097152
  u16* opl   = (u16*)(ws + D0);                       // 3 planes, pl 8388608
  u16* t1b   = (u16*)(ws + D0);
  u16* asb   = (u16*)(ws + D0 + 16777216ull);
  u16* aeb   = (u16*)(ws + D0);
  u16* qpl   = (u16*)(ws + D1);                       // 2 planes, pl 12582912
  u16* wexp  = (u16*)(ws + D1);
  u16* swp   = (u16*)(ws + D1 + 25165824ull);
  u16* vtp   = (u16*)(ws + D2);                       // 3 planes, pl 8388608
  float* firstb = (float*)(ws + D2);
  u16* h2b   = (u16*)(ws + D2 + 33554432ull);
  u16* wqp   = (u16*)(ws + D3);                       // 3 planes, pl 6291456
  u16* wkvap = (u16*)(ws + D3);                       // 3 planes, pl 1179648
  float* kvr = (float*)(ws + D3 + 7077888ull);
  u16* kpl0  = (u16*)(ws + D3);                       // 2 planes, pl 8388608
  u16* kpl1  = kpl0 + 8388608ull;
  u16* kpe0  = (u16*)(ws + D3 + 33554432ull);
  u16* kpe1  = kpe0 + 262144ull;
  u16* wop   = (u16*)(ws + D3);                       // 3 planes, pl 4194304
  u16* y1eb  = (u16*)(ws + D3);
  float* cosT = (float*)(ws + SM);
  float* sinT = (float*)(ws + SM + 262144ull);
  int*   idxb = (int*)(ws + SM + 524288ull);
  float* gw4b = (float*)(ws + SM + 589824ull);
  int*   listb= (int*)(ws + SM + 655360ull);
  float* gwsb = (float*)(ws + SM + 720896ull);
  int*   cntb = (int*)(ws + SM + 786432ull);
  int*   curb = (int*)(ws + SM + 786688ull);
  int*   baseb= (int*)(ws + SM + 786944ull);

  const size_t PL_TD = (size_t)TKN * DIM;  // 8388608

  hipMemsetAsync(cntb, 0, 256, stream);
  rope_table<<<dim3(256), 256, 0, stream>>>(cosT, sinT, sp);
  rmsnorm3<<<dim3(TKN), 256, 0, stream>>>(x, norm_w, hpl);

  // q = h @ wq^T  (fused RoPE + 2-plane split out); 4 products (x2*x2) —
  // q is consumed at x2-split precision, so f32-grade (6 prod) is wasted here
  split3<<<dim3(1024), 256, 0, stream>>>(wq, wqp, (size_t)3072 * 2048, 6291456ull);
  gemm_f<EF_QROPE, AM_DIR, 4><<<dim3(32, 24), 256, 0, stream>>>(
      hpl, wqp, nullptr, TKN, 3072, 2048, PL_TD, 6291456ull,
      nullptr, nullptr, nullptr, sinT, nullptr, qpl, qpl + 12582912ull, nullptr, cosT);

  // kv = h @ wkv_a^T (f32)
  split3<<<dim3(512), 256, 0, stream>>>(wkv_a, wkvap, (size_t)576 * 2048, 1179648ull);
  gemm_f<EF_F32, AM_DIR, 6><<<dim3(32, 5), 256, 0, stream>>>(
      hpl, wkvap, kvr, TKN, 576, 2048, PL_TD, 1179648ull,
      nullptr, nullptr, nullptr, nullptr, nullptr, nullptr, nullptr, nullptr, nullptr);

  kv_split<<<dim3(TKN), 256, 0, stream>>>(kvr, kvnw, cpl, kpe0, kpe1, cosT, sinT);

  // k_nope/v = c @ wkv_b^T (split K planes + transposed V planes)
  split3<<<dim3(1024), 256, 0, stream>>>(wkv_b, wkvbp, (size_t)4096 * 512, 2097152ull);
  gemm_f<EF_KV, AM_DIR, 6><<<dim3(32, 32), 256, 0, stream>>>(
      cpl, wkvbp, nullptr, TKN, 4096, 512, 2097152ull, 2097152ull,
      nullptr, nullptr, nullptr, nullptr, nullptr, kpl0, kpl1, vtp, nullptr);

  attn3<<<dim3(16, 32), 256, 0, stream>>>(qpl, qpl + 12582912ull, kpl0, kpl1,
      kpe0, kpe1, vtp, opl, 1.f / sqrtf(192.f));

  // first = o @ wo^T + x
  split3<<<dim3(1024), 256, 0, stream>>>(wo, wop, (size_t)2048 * 2048, 4194304ull);
  gemm_f<EF_RES, AM_DIR, 6><<<dim3(32, 16), 256, 0, stream>>>(
      opl, wop, firstb, TKN, 2048, 2048, PL_TD, 4194304ull,
      nullptr, nullptr, nullptr, x, nullptr, nullptr, nullptr, nullptr, nullptr);

  rmsnorm1<<<dim3(TKN), 256, 0, stream>>>(firstb, norm_w, h2b);
  gate_topk<<<dim3(TKN), 256, 0, stream>>>(firstb, norm_w, gatew, gateb, idxb, gw4b, cntb);
  prefix12<<<dim3(1), 64, 0, stream>>>(cntb, baseb, curb);
  fill_lists<<<dim3(16), 256, 0, stream>>>(idxb, baseb, curb, listb, gw4b, gwsb);

  // shared expert -> out (write)
  cvt1<<<dim3(1024), 256, 0, stream>>>(sw1, swp, (size_t)2048 * 2048);
  cvt1<<<dim3(1024), 256, 0, stream>>>(sw3, swp + 4194304ull, (size_t)2048 * 2048);
  cvt1<<<dim3(1024), 256, 0, stream>>>(sw2, swp + 8388608ull, (size_t)2048 * 2048);
  gemm_f<EF_BF16, AM_DIR, 1><<<dim3(32, 16), 256, 0, stream>>>(
      h2b, swp, t1b, TKN, 2048, 2048, 0, 0,
      nullptr, nullptr, nullptr, nullptr, nullptr, nullptr, nullptr, nullptr, nullptr);
  gemm_f<EF_SILU, AM_DIR, 1><<<dim3(32, 16), 256, 0, stream>>>(
      h2b, swp + 4194304ull, asb, TKN, 2048, 2048, 0, 0,
      nullptr, nullptr, nullptr, t1b, nullptr, nullptr, nullptr, nullptr, nullptr);
  gemm_f<EF_F32, AM_DIR, 1><<<dim3(32, 16), 256, 0, stream>>>(
      asb, swp + 8388608ull, out, TKN, 2048, 2048, 0, 0,
      nullptr, nullptr, nullptr, nullptr, nullptr, nullptr, nullptr, nullptr, nullptr);

  // routed experts (two groups of 6), scatter-add into out
  for (int g = 0; g < 2; g++) {
    cvt1<<<dim3(2048), 256, 0, stream>>>(w1 + (size_t)g * 6 * 1024 * 2048, wexp,
                                         (size_t)6 * 1024 * 2048);
    gemm_f<EF_BF16, AM_LIST, 1><<<dim3(32, 8, 6), 256, 0, stream>>>(
        h2b, wexp, y1eb, 0, 1024, 2048, 0, 0,
        listb, baseb + g * 6, cntb + g * 6, nullptr, nullptr, nullptr, nullptr, nullptr, nullptr);
    cvt1<<<dim3(2048), 256, 0, stream>>>(w3 + (size_t)g * 6 * 1024 * 2048, wexp,
                                         (size_t)6 * 1024 * 2048);
    gemm_f<EF_SILU, AM_LIST, 1><<<dim3(32, 8, 6), 256, 0, stream>>>(
        h2b, wexp, aeb, 0, 1024, 2048, 0, 0,
        listb, baseb + g * 6, cntb + g * 6, y1eb, nullptr, nullptr, nullptr, nullptr, nullptr);
    cvt1<<<dim3(2048), 256, 0, stream>>>(w2 + (size_t)g * 6 * 2048 * 1024, wexp,
                                         (size_t)6 * 2048 * 1024);
    gemm_f<EF_ATOM, AM_OFF, 1><<<dim3(32, 16, 6), 256, 0, stream>>>(
        aeb, wexp, out, 0, 2048, 1024, 0, 0,
        listb, baseb + g * 6, cntb + g * 6, nullptr, gwsb, nullptr, nullptr, nullptr, nullptr);
  }

  final_add<<<dim3(2048), 256, 0, stream>>>(out, firstb);
}